// Round 18
// baseline (185.811 us; speedup 1.0000x reference)
//
#include <hip/hip_runtime.h>
#include <math.h>

#pragma clang fp contract(off)

#define NLVL 5
#define TOTALN 261888
#define NBATCH 16
#define CAP 1024
#define NPROB (NBATCH * NLVL)
#define POST_N 1000
#define NMS_TH 0.7f
#define MINSZ 1e-3f
#define IMGSZ 1024.0f
#define BBOX_CLIP 4.135166556742356f

// exact midpoint between 0.7f and nextafterf(0.7f): fl32(a/b) > 0.7f  <=>  a >= M_TH*b (b>0)
// (0.7f mantissa odd -> round-to-nearest-even sends the tie upward -> ">="); 25-bit M_TH
// times 24-bit un is exact in double, and (double)inter is exact -> predicate is exact.
// Fast path: M_TH*un = 0.7f*un + 2^-25*un, so condition is real(inter - 0.7f*un) >= 2^-25*un.
// d = fmaf(-0.7f,un,inter) is that real value with ONE rounding; t = un*2^-25 is EXACT.
// If |fl(d-t)| > 2^-14*max(|d|,t), sign(fl(d-t)) == sign(real - t) (error chain:
// |d-real| <= 2^-24|d|, |fl(d-t)-(d-t)| <= 2^-24|fl(d-t)| -- both << window), so the
// f32 decision is exact; otherwise fall back to the f64 predicate (wave-uniform, ~0.4%).
#define M_TH 0x1.666667p-1

#define HBINS 2048
#define CCAP 4096
#define NCHUNK 256   // ceil(261888/1024); level offsets are all multiples of 1024
#define LMS 17       // LDS mask row stride in u64 words (bank-spread for row gathers)
#define NPAIR 136    // (w, rc<=w) wave-pairs per problem; 34 blocks x 4 waves

__constant__ int c_loff[NLVL] = {0, 196608, 245760, 258048, 261120};
__constant__ int c_num[NLVL]  = {196608, 49152, 12288, 3072, 768};
__constant__ int c_k[NLVL]    = {1000, 1000, 1000, 1000, 768};
__constant__ int c_nch[NLVL]  = {192, 48, 12, 3, 1};   // hist chunks per level

// pair q -> (word w, row-chunk rc), rc <= w, q = w(w+1)/2 + rc
__constant__ unsigned char c_pw[NPAIR] = {
    0, 1,1, 2,2,2, 3,3,3,3, 4,4,4,4,4, 5,5,5,5,5,5, 6,6,6,6,6,6,6,
    7,7,7,7,7,7,7,7, 8,8,8,8,8,8,8,8,8, 9,9,9,9,9,9,9,9,9,9,
    10,10,10,10,10,10,10,10,10,10,10, 11,11,11,11,11,11,11,11,11,11,11,11,
    12,12,12,12,12,12,12,12,12,12,12,12,12, 13,13,13,13,13,13,13,13,13,13,13,13,13,13,
    14,14,14,14,14,14,14,14,14,14,14,14,14,14,14,
    15,15,15,15,15,15,15,15,15,15,15,15,15,15,15,15};
__constant__ unsigned char c_pr[NPAIR] = {
    0, 0,1, 0,1,2, 0,1,2,3, 0,1,2,3,4, 0,1,2,3,4,5, 0,1,2,3,4,5,6,
    0,1,2,3,4,5,6,7, 0,1,2,3,4,5,6,7,8, 0,1,2,3,4,5,6,7,8,9,
    0,1,2,3,4,5,6,7,8,9,10, 0,1,2,3,4,5,6,7,8,9,10,11,
    0,1,2,3,4,5,6,7,8,9,10,11,12, 0,1,2,3,4,5,6,7,8,9,10,11,12,13,
    0,1,2,3,4,5,6,7,8,9,10,11,12,13,14,
    0,1,2,3,4,5,6,7,8,9,10,11,12,13,14,15};

__device__ __forceinline__ unsigned monokey(float f) {
    unsigned b = __float_as_uint(f);
    return (b & 0x80000000u) ? ~b : (b | 0x80000000u);
}

__device__ __forceinline__ int lvl_of_start(int start) {
    return (start >= 261120) ? 4 : (start >= 258048) ? 3 : (start >= 245760) ? 2
         : (start >= 196608) ? 1 : 0;
}

// ---------------- pass 1: per-chunk LDS histogram + fused last-block threshold pick ----
__global__ __launch_bounds__(256) void hist_kernel(const float* __restrict__ obj_all,
                                                   unsigned* __restrict__ ghist,
                                                   int* __restrict__ donecnt,
                                                   unsigned* __restrict__ b1out) {
    __shared__ unsigned lh[HBINS];
    __shared__ int s_last;
    const int tid = threadIdx.x;
    const int chunk = blockIdx.x;
    const int img = chunk >> 8, c = chunk & 255;
    const int start = c << 10;
    const int lvl = lvl_of_start(start);
    const int nrem = min(1024, TOTALN - start);
    const int p = img * NLVL + lvl;
    for (int i = tid; i < HBINS; i += 256) lh[i] = 0;
    __syncthreads();
    const float* o = obj_all + (size_t)img * TOTALN + start;
    for (int i = tid; i < nrem; i += 256) atomicAdd(&lh[monokey(o[i]) >> 21], 1u);
    __syncthreads();
    unsigned* gh = ghist + (size_t)p * HBINS;
    for (int i = tid; i < HBINS; i += 256) {
        unsigned v = lh[i];
        if (v) atomicAdd(&gh[i], v);
    }
    __syncthreads();   // barrier drains vmcnt -> this block's ghist atomics are complete
    if (tid == 0) s_last = (atomicAdd(&donecnt[p], 1) == c_nch[lvl] - 1) ? 1 : 0;
    __syncthreads();
    if (!s_last) return;

    // last block for problem p: coherent re-read + suffix-sum threshold pick
    for (int i = tid; i < HBINS; i += 256) lh[i] = atomicAdd(&gh[i], 0u);
    __syncthreads();
    const int k = c_k[lvl];
    for (int d = 1; d < HBINS; d <<= 1) {
        unsigned v[HBINS / 256];
#pragma unroll
        for (int r = 0; r < HBINS / 256; ++r) {
            int i = tid + r * 256;
            v[r] = lh[i] + ((i + d < HBINS) ? lh[i + d] : 0u);
        }
        __syncthreads();
#pragma unroll
        for (int r = 0; r < HBINS / 256; ++r) lh[tid + r * 256] = v[r];
        __syncthreads();
    }
#pragma unroll
    for (int r = 0; r < HBINS / 256; ++r) {
        int i = tid + r * 256;
        if (lh[i] >= (unsigned)k && (i == HBINS - 1 || lh[i + 1] < (unsigned)k))
            b1out[p] = (unsigned)i;
    }
}

// ---------------- pass 2: compact all keys >= (b1<<21) ----------------
__global__ __launch_bounds__(256) void compact_kernel(const float* __restrict__ obj_all,
                                                      const unsigned* __restrict__ b1in,
                                                      int* __restrict__ cnt,
                                                      unsigned long long* __restrict__ cand) {
    __shared__ unsigned long long lkey[1024];
    __shared__ int s_lc, s_base;
    const int tid = threadIdx.x;
    const int chunk = blockIdx.x;
    const int img = chunk >> 8, c = chunk & 255;
    const int start = c << 10;
    const int lvl = lvl_of_start(start);
    const int nrem = min(1024, TOTALN - start);
    const int p = img * NLVL + lvl;
    const unsigned thr = b1in[p] << 21;
    const int local0 = start - c_loff[lvl];
    if (tid == 0) s_lc = 0;
    __syncthreads();
    const float* o = obj_all + (size_t)img * TOTALN + start;
    for (int i = tid; i < nrem; i += 256) {
        unsigned key = monokey(o[i]);
        if (key >= thr) {
            int l = atomicAdd(&s_lc, 1);
            lkey[l] = (((unsigned long long)key) << 32) | (unsigned)(~(unsigned)(local0 + i));
        }
    }
    __syncthreads();
    if (tid == 0) s_base = atomicAdd(&cnt[p], s_lc);
    __syncthreads();
    const int lc = s_lc, base = s_base;
    unsigned long long* cd = cand + (size_t)p * CCAP;
    for (int i = tid; i < lc; i += 256) {
        int pos = base + i;
        if (pos < CCAP) cd[pos] = lkey[i];
    }
}

// ---------------- rank + decode fused: 32-deep LDS batches (MLP), 4 accumulators ------
__global__ __launch_bounds__(256) void rankdec_kernel(
    const unsigned long long* __restrict__ cand, const int* __restrict__ cnt,
    const float* __restrict__ obj_all, const float* __restrict__ deltas,
    const float* __restrict__ anchors,
    float4* __restrict__ cbox, float* __restrict__ csc, float* __restrict__ carea) {
    __shared__ unsigned long long skey[CCAP];
    const int p = blockIdx.x >> 4;
    const int blk = blockIdx.x & 15;
    const int tid = threadIdx.x;
    const int lvl = p % NLVL, img = p / NLVL, k = c_k[lvl];
    int n = cnt[p]; if (n > CCAP) n = CCAP;
    const int i0 = blk << 8;
    if (i0 >= n) return;                       // block-uniform exit, no barrier crossed
    const unsigned long long* cd = cand + (size_t)p * CCAP;
    const int n32 = (n + 31) & ~31;
    for (int i = tid; i < n32; i += 256) skey[i] = (i < n) ? cd[i] : 0ull;
    __syncthreads();
    const int i = i0 + tid;
    const unsigned long long my = (i < n) ? skey[i] : ~0ull;  // sentinel -> rank 0, not emitted
    int r0 = 0, r1 = 0, r2 = 0, r3 = 0;
    for (int j = 0; j < n32; j += 32) {        // 32 wave-uniform LDS reads in flight
        unsigned long long kk[32];
#pragma unroll
        for (int q = 0; q < 32; ++q) kk[q] = skey[j + q];
#pragma unroll
        for (int q = 0; q < 8; ++q) {
            r0 += (int)(kk[q] > my);
            r1 += (int)(kk[8 + q] > my);
            r2 += (int)(kk[16 + q] > my);
            r3 += (int)(kk[24 + q] > my);
        }
    }
    const int rank = (r0 + r1) + (r2 + r3);
    if (i < n && rank < k) {
        unsigned li = ~(unsigned)(my & 0xFFFFFFFFull);
        unsigned idx = (unsigned)c_loff[lvl] + li;
        float o = obj_all[(size_t)img * TOTALN + idx];
        const float4 dd = *(const float4*)(deltas + ((size_t)img * TOTALN + (size_t)idx) * 4);
        const float4 aa = *(const float4*)(anchors + (size_t)idx * 4);
        float a0 = aa.x, a1 = aa.y, a2 = aa.z, a3 = aa.w;
        float w = a2 - a0, h = a3 - a1;
        float cx = a0 + 0.5f * w, cy = a1 + 0.5f * h;
        float dx = dd.x, dy = dd.y;
        float dw = fminf(dd.z, BBOX_CLIP), dh = fminf(dd.w, BBOX_CLIP);
        float pcx = dx * w + cx, pcy = dy * h + cy;
        float pw = expf(dw) * w, ph = expf(dh) * h;
        float bx1 = pcx - 0.5f * pw, by1 = pcy - 0.5f * ph;
        float bx2 = pcx + 0.5f * pw, by2 = pcy + 0.5f * ph;
        float x1 = fminf(fmaxf(bx1, 0.f), IMGSZ);
        float y1 = fminf(fmaxf(by1, 0.f), IMGSZ);
        float x2 = fminf(fmaxf(bx2, 0.f), IMGSZ);
        float y2 = fminf(fmaxf(by2, 0.f), IMGSZ);
        float wsz = x2 - x1, hsz = y2 - y1;
        float scv = (wsz >= MINSZ && hsz >= MINSZ) ? 1.0f / (1.0f + expf(-o)) : 0.0f;
        cbox[(size_t)p * CAP + rank] = make_float4(x1, y1, x2, y2);
        csc[(size_t)p * CAP + rank] = scv;
        carea[(size_t)p * CAP + rank] = wsz * hsz;   // same expression the mask used
    }
}

// ---------------- NMS phase 1: ballot-form mask, wave = one (word, 64-row chunk) -------
// f32 fast predicate + provably-safe rare f64 fallback (see M_TH comment above).
__global__ __launch_bounds__(256) void mask_kernel(const float4* __restrict__ cbox,
                                                   const float* __restrict__ carea,
                                                   unsigned long long* __restrict__ gmaskT,
                                                   unsigned long long* __restrict__ tdiag) {
    const int bid = blockIdx.x;
    const int p = bid / 34;
    const int wid = __builtin_amdgcn_readfirstlane(threadIdx.x >> 6);
    const int lane = threadIdx.x & 63;
    const int q = (bid - p * 34) * 4 + wid;           // 0..135, SGPR
    const int w = c_pw[q], rc = c_pr[q];              // SGPR via scalar loads
    const int base = p * CAP;

    const float4 cb = cbox[base + (w << 6) + lane];   // column box, per-lane registers
    const float car = carea[base + (w << 6) + lane];
    const float4* rowb = cbox + base + (rc << 6);     // wave-uniform row pointers
    const float* rowa = carea + base + (rc << 6);

    unsigned long long tbits = 0, myword = 0;
    const bool isdiag = (rc == w);                    // wave-uniform
#pragma unroll 8
    for (int r = 0; r < 64; ++r) {
        const float4 rb = rowb[r];                    // s_load_dwordx4 (uniform)
        const float ar = rowa[r];                     // s_load_dword  (uniform)
        float ltx = fmaxf(rb.x, cb.x), lty = fmaxf(rb.y, cb.y);
        float rbx = fminf(rb.z, cb.z), rby = fminf(rb.w, cb.w);
        float wx = fmaxf(rbx - ltx, 0.f), wy = fmaxf(rby - lty, 0.f);
        float inter = wx * wy;
        float un = (ar + car) - inter;
        const bool unpos = un > 0.f;
        float d = fmaf(-NMS_TH, un, inter);           // fl(inter - 0.7f*un), 1 rounding
        float t = un * 0x1p-25f;                      // exact
        float ddf = d - t;
        bool near = unpos && (fabsf(ddf) <= 0x1p-14f * fmaxf(fabsf(d), t));
        bool sup;
        if (__ballot(near) != 0ull) {                 // rare, wave-uniform fallback
            sup = unpos && ((double)inter >= M_TH * (double)un);
        } else {
            sup = unpos && (ddf >= 0.f);
        }
        unsigned long long bits = __ballot(sup);
        if (isdiag) {
            bits &= (0xFFFFFFFFFFFFFFFEull << r);     // keep col > row within the chunk
            if (sup && lane > r) tbits |= (1ull << r);
        }
        myword = (lane == r) ? bits : myword;
    }
    gmaskT[((size_t)p << 14) + ((size_t)w << 10) + (rc << 6) + lane] = myword;
    if (isdiag) tdiag[((size_t)p << 10) + (w << 6) + lane] = tbits;
}

// ---------------- NMS phase 2: bulk mask->LDS + word-level fixpoint greedy scan --------
__global__ __launch_bounds__(1024) void scan_kernel(
    const unsigned long long* __restrict__ gmaskT,
    const unsigned long long* __restrict__ tdiag,
    const float4* __restrict__ cbox, const float* __restrict__ csc,
    float* __restrict__ svbox, float* __restrict__ svsc, int* __restrict__ svcnt) {
    __shared__ unsigned long long lm[CAP * LMS];
    __shared__ float ssc[CAP];
    __shared__ unsigned short survL[CAP];
    __shared__ int s_ns;
    const int p = blockIdx.x, tid = threadIdx.x;
    const int lvl = p % NLVL, k = c_k[lvl];
    const int base = p * CAP;

    {   // copy transposed mask -> LDS[row*17 + w] (coalesced reads; 17-stride de-bank)
        const ulonglong2* g2 = (const ulonglong2*)(gmaskT + ((size_t)p << 14));
#pragma unroll
        for (int c = 0; c < 8; ++c) {
            ulonglong2 v = g2[c * 1024 + tid];
            const int e = (c * 1024 + tid) << 1;      // u64 index = w*1024 + row
            const int w = e >> 10, row = e & 1023;
            lm[row * LMS + w] = v.x;
            lm[(row + 1) * LMS + w] = v.y;
        }
        ssc[tid] = (tid < k) ? csc[base + tid] : 0.f;  // k-guard: no csc memset needed
    }
    __syncthreads();

    if (tid < 64) {
        const int lane = tid;
        const unsigned long long* td = tdiag + ((size_t)p << 10);
        unsigned long long tg = td[lane];             // group 0 transposed diagonal
        const unsigned long long mybit = 1ull << lane;
        const unsigned long long below = mybit - 1ull;
        int ns = 0;
        for (int g = 0; g < 16; ++g) {
            unsigned long long tgn = (g < 15) ? td[((g + 1) << 6) + lane] : 0ull;
            unsigned long long wv = __ballot(ssc[(g << 6) + lane] <= 0.f);
            // cross-group suppression: OR word g over all prior accepts (off-chain MLP)
            unsigned long long a0 = 0, a1 = 0, a2 = 0, a3 = 0;
            int j = lane;
            for (; j + 192 < ns; j += 256) {
                int r0 = survL[j], r1 = survL[j + 64];
                int r2 = survL[j + 128], r3 = survL[j + 192];
                a0 |= lm[r0 * LMS + g];
                a1 |= lm[r1 * LMS + g];
                a2 |= lm[r2 * LMS + g];
                a3 |= lm[r3 * LMS + g];
            }
            for (; j < ns; j += 64) a0 |= lm[((int)survL[j]) * LMS + g];
            unsigned long long accw = (a0 | a1) | (a2 | a3);
#pragma unroll
            for (int d2 = 1; d2 < 64; d2 <<= 1)
                accw |= (unsigned long long)__shfl_xor((unsigned long long)accw, d2);

            const unsigned long long alive = ~(wv | accw);
            unsigned long long A = alive;
#pragma unroll 1
            for (int it = 0; it < 64; ++it) {      // fixpoint -> exact greedy set
                bool kill = (tg & A) != 0ull;
                unsigned long long An = alive & ~__ballot(kill);
                if (An == A) break;
                A = An;
            }
            if (A & mybit)                          // parallel, order-preserving emission
                survL[ns + __popcll(A & below)] = (unsigned short)((g << 6) + lane);
            ns += __popcll(A);
            tg = tgn;
        }
        if (lane == 0) s_ns = ns;
    }
    __syncthreads();

    const int ns = s_ns;
    for (int s = tid; s < ns; s += 1024) {
        int r = survL[s];
        svsc[base + s] = ssc[r];
        *(float4*)(svbox + ((size_t)(base + s)) * 4) = cbox[base + r];
    }
    if (tid == 0) svcnt[p] = ns;
}

// ---------------- merge: 80 blocks (img,level); branchless bit-descent rank ----------
__global__ __launch_bounds__(256) void merge_kernel(
    const float* __restrict__ svbox, const float* __restrict__ svsc,
    const int* __restrict__ svcnt, float* __restrict__ out) {
    __shared__ float sls[NLVL][CAP];
    __shared__ int scnt[NLVL];
    const int img = blockIdx.x / NLVL, l = blockIdx.x % NLVL;
    const int tid = threadIdx.x;
    if (tid < NLVL) scnt[tid] = svcnt[img * NLVL + tid];
    __syncthreads();
    for (int m = 0; m < NLVL; ++m) {
        int c = scnt[m];
        for (int i = tid; i < c; i += 256) sls[m][i] = svsc[(img * NLVL + m) * CAP + i];
    }
    __syncthreads();
    const int c = scnt[l];
    for (int i = tid; i < c; i += 256) {
        const float s = sls[l][i];
        int pos = i;
#pragma unroll
        for (int m = 0; m < NLVL; ++m) {
            if (m == l) continue;
            const int n2 = scnt[m];
            int lo = 0;
#pragma unroll
            for (int st = 512; st > 0; st >>= 1) {
                const int idx = lo + st;
                const bool ok = (idx <= n2);
                const float v = sls[m][ok ? idx - 1 : 0];   // in-bounds; unused if !ok
                const bool ahead = (m < l) ? (v >= s) : (v > s);
                if (ok && ahead) lo = idx;
            }
            pos += lo;
        }
        if (pos < POST_N) {
            const int src = (img * NLVL + l) * CAP + i;
            float* o = out + ((size_t)img * POST_N + pos) * 5;
            o[0] = svbox[(size_t)src * 4 + 0];
            o[1] = svbox[(size_t)src * 4 + 1];
            o[2] = svbox[(size_t)src * 4 + 2];
            o[3] = svbox[(size_t)src * 4 + 3];
            o[4] = s;
        }
    }
}

extern "C" void kernel_launch(void* const* d_in, const int* in_sizes, int n_in,
                              void* d_out, int out_size, void* d_ws, size_t ws_size,
                              hipStream_t stream) {
    const float* obj     = (const float*)d_in[0];
    const float* deltas  = (const float*)d_in[1];
    const float* anchors = (const float*)d_in[2];
    float* out = (float*)d_out;

    char* w = (char*)d_ws;
    size_t off = 0;
    auto alloc = [&](size_t bytes) -> void* {
        void* pp = w + off;
        off += (bytes + 511) & ~(size_t)511;
        return pp;
    };
    // zeroed region: ghist + donecnt + ccnt cleared with ONE memset
    size_t z0 = off;
    unsigned* ghist   = (unsigned*)alloc((size_t)NPROB * HBINS * 4);
    int*      donecnt = (int*)alloc((size_t)NPROB * 4);
    int*      ccnt    = (int*)alloc((size_t)NPROB * 4);
    size_t zspan = off - z0;
    unsigned* b1buf = (unsigned*)alloc((size_t)NPROB * 4);
    unsigned long long* cand = (unsigned long long*)alloc((size_t)NPROB * CCAP * 8);
    float4*   cbox  = (float4*)alloc((size_t)NPROB * CAP * 16);
    float*    csc   = (float*)alloc((size_t)NPROB * CAP * 4);
    float*    carea = (float*)alloc((size_t)NPROB * CAP * 4);
    unsigned long long* gmaskT = (unsigned long long*)alloc((size_t)NPROB * CAP * 16 * 8);
    unsigned long long* tdiag = (unsigned long long*)alloc((size_t)NPROB * CAP * 8);
    float* svbox = (float*)alloc((size_t)NPROB * CAP * 16);
    float* svsc  = (float*)alloc((size_t)NPROB * CAP * 4);
    int*   svcnt = (int*)alloc((size_t)NPROB * 4);
    if (off > ws_size) return;  // fail cleanly (output stays poisoned -> visible failure)

    hipMemsetAsync(ghist, 0, zspan, stream);
    hipMemsetAsync(d_out, 0, (size_t)out_size * sizeof(float), stream);

    hist_kernel<<<NBATCH * NCHUNK, 256, 0, stream>>>(obj, ghist, donecnt, b1buf);
    compact_kernel<<<NBATCH * NCHUNK, 256, 0, stream>>>(obj, b1buf, ccnt, cand);
    rankdec_kernel<<<NPROB * 16, 256, 0, stream>>>(cand, ccnt, obj, deltas, anchors,
                                                   cbox, csc, carea);
    mask_kernel<<<NPROB * 34, 256, 0, stream>>>(cbox, carea, gmaskT, tdiag);
    scan_kernel<<<NPROB, 1024, 0, stream>>>(gmaskT, tdiag, cbox, csc, svbox, svsc, svcnt);
    merge_kernel<<<NPROB, 256, 0, stream>>>(svbox, svsc, svcnt, out);
}

// Round 19
// 140.596 us; speedup vs baseline: 1.3216x; 1.3216x over previous
//
#include <hip/hip_runtime.h>
#include <math.h>

#pragma clang fp contract(off)

#define NLVL 5
#define TOTALN 261888
#define NBATCH 16
#define CAP 1024
#define NPROB (NBATCH * NLVL)
#define POST_N 1000
#define NMS_TH 0.7f
#define MINSZ 1e-3f
#define IMGSZ 1024.0f
#define BBOX_CLIP 4.135166556742356f

// exact midpoint between 0.7f and nextafterf(0.7f): fl32(a/b) > 0.7f  <=>  a >= M_TH*b (b>0)
// (0.7f mantissa odd -> round-to-nearest-even sends the tie upward -> ">="); 25-bit M_TH
// times 24-bit un is exact in double, and (double)inter is exact -> predicate is exact.
#define M_TH 0x1.666667p-1

#define HBINS 2048
#define CCAP 4096
#define NBLK 65      // hist/compact blocks per image (48+12+3+1+1)
#define LMS 17       // LDS mask row stride in u64 words (bank-spread for row gathers)
#define NPAIR 136    // (w, rc<=w) wave-pairs per problem; 34 blocks x 4 waves

__constant__ int c_loff[NLVL] = {0, 196608, 245760, 258048, 261120};
__constant__ int c_k[NLVL]    = {1000, 1000, 1000, 1000, 768};
__constant__ int c_nch[NLVL]  = {48, 12, 3, 1, 1};     // hist/compact blocks per level

// pair q -> (word w, row-chunk rc), rc <= w, q = w(w+1)/2 + rc
__constant__ unsigned char c_pw[NPAIR] = {
    0, 1,1, 2,2,2, 3,3,3,3, 4,4,4,4,4, 5,5,5,5,5,5, 6,6,6,6,6,6,6,
    7,7,7,7,7,7,7,7, 8,8,8,8,8,8,8,8,8, 9,9,9,9,9,9,9,9,9,9,
    10,10,10,10,10,10,10,10,10,10,10, 11,11,11,11,11,11,11,11,11,11,11,11,
    12,12,12,12,12,12,12,12,12,12,12,12,12, 13,13,13,13,13,13,13,13,13,13,13,13,13,13,
    14,14,14,14,14,14,14,14,14,14,14,14,14,14,14,
    15,15,15,15,15,15,15,15,15,15,15,15,15,15,15,15};
__constant__ unsigned char c_pr[NPAIR] = {
    0, 0,1, 0,1,2, 0,1,2,3, 0,1,2,3,4, 0,1,2,3,4,5, 0,1,2,3,4,5,6,
    0,1,2,3,4,5,6,7, 0,1,2,3,4,5,6,7,8, 0,1,2,3,4,5,6,7,8,9,
    0,1,2,3,4,5,6,7,8,9,10, 0,1,2,3,4,5,6,7,8,9,10,11,
    0,1,2,3,4,5,6,7,8,9,10,11,12, 0,1,2,3,4,5,6,7,8,9,10,11,12,13,
    0,1,2,3,4,5,6,7,8,9,10,11,12,13,14,
    0,1,2,3,4,5,6,7,8,9,10,11,12,13,14,15};

__device__ __forceinline__ unsigned monokey(float f) {
    unsigned b = __float_as_uint(f);
    return (b & 0x80000000u) ? ~b : (b | 0x80000000u);
}

// block b in [0,NBLK) -> (lvl, start, cnt); spans never straddle levels
__device__ __forceinline__ void blk_span(int b, int& lvl, int& start, int& cnt) {
    if (b < 48)      { lvl = 0; start = b * 4096;                  cnt = 4096; }
    else if (b < 60) { lvl = 1; start = 196608 + (b - 48) * 4096;  cnt = 4096; }
    else if (b < 63) { lvl = 2; start = 245760 + (b - 60) * 4096;  cnt = 4096; }
    else if (b == 63){ lvl = 3; start = 258048;                    cnt = 3072; }
    else             { lvl = 4; start = 261120;                    cnt = 768;  }
}

// ---------------- pass 1: 4096-elem float4 histogram + fused last-block pick ----------
__global__ __launch_bounds__(256) void hist_kernel(const float* __restrict__ obj_all,
                                                   unsigned* __restrict__ ghist,
                                                   int* __restrict__ donecnt,
                                                   unsigned* __restrict__ b1out) {
    __shared__ unsigned lh[HBINS];
    __shared__ int s_last;
    const int tid = threadIdx.x;
    const int img = blockIdx.x / NBLK, b = blockIdx.x - img * NBLK;
    int lvl, start, cnt;
    blk_span(b, lvl, start, cnt);
    const int p = img * NLVL + lvl;
    for (int i = tid; i < HBINS; i += 256) lh[i] = 0;
    __syncthreads();
    const float* o = obj_all + (size_t)img * TOTALN + start;
    for (int i = tid * 4; i < cnt; i += 1024) {        // float4: 16B/lane coalesced
        float4 v = *(const float4*)(o + i);
        atomicAdd(&lh[monokey(v.x) >> 21], 1u);
        atomicAdd(&lh[monokey(v.y) >> 21], 1u);
        atomicAdd(&lh[monokey(v.z) >> 21], 1u);
        atomicAdd(&lh[monokey(v.w) >> 21], 1u);
    }
    __syncthreads();
    unsigned* gh = ghist + (size_t)p * HBINS;
    for (int i = tid; i < HBINS; i += 256) {
        unsigned v = lh[i];
        if (v) atomicAdd(&gh[i], v);
    }
    __syncthreads();   // barrier drains vmcnt -> this block's ghist atomics are complete
    if (tid == 0) s_last = (atomicAdd(&donecnt[p], 1) == c_nch[lvl] - 1) ? 1 : 0;
    __syncthreads();
    if (!s_last) return;

    // last block for problem p: coherent re-read + suffix-sum threshold pick
    for (int i = tid; i < HBINS; i += 256) lh[i] = atomicAdd(&gh[i], 0u);
    __syncthreads();
    const int k = c_k[lvl];
    for (int d = 1; d < HBINS; d <<= 1) {
        unsigned v[HBINS / 256];
#pragma unroll
        for (int r = 0; r < HBINS / 256; ++r) {
            int i = tid + r * 256;
            v[r] = lh[i] + ((i + d < HBINS) ? lh[i + d] : 0u);
        }
        __syncthreads();
#pragma unroll
        for (int r = 0; r < HBINS / 256; ++r) lh[tid + r * 256] = v[r];
        __syncthreads();
    }
#pragma unroll
    for (int r = 0; r < HBINS / 256; ++r) {
        int i = tid + r * 256;
        if (lh[i] >= (unsigned)k && (i == HBINS - 1 || lh[i + 1] < (unsigned)k))
            b1out[p] = (unsigned)i;
    }
}

// ---------------- pass 2: compact all keys >= (b1<<21), 4096-elem float4 blocks -------
__global__ __launch_bounds__(256) void compact_kernel(const float* __restrict__ obj_all,
                                                      const unsigned* __restrict__ b1in,
                                                      int* __restrict__ cnt,
                                                      unsigned long long* __restrict__ cand) {
    __shared__ unsigned long long lkey[4096];
    __shared__ int s_lc, s_base;
    const int tid = threadIdx.x;
    const int img = blockIdx.x / NBLK, b = blockIdx.x - img * NBLK;
    int lvl, start, nrem;
    blk_span(b, lvl, start, nrem);
    const int p = img * NLVL + lvl;
    const unsigned thr = b1in[p] << 21;
    const int local0 = start - c_loff[lvl];
    if (tid == 0) s_lc = 0;
    __syncthreads();
    const float* o = obj_all + (size_t)img * TOTALN + start;
    for (int i = tid * 4; i < nrem; i += 1024) {
        float4 v = *(const float4*)(o + i);
        unsigned kx = monokey(v.x), ky = monokey(v.y);
        unsigned kz = monokey(v.z), kw = monokey(v.w);
        if (kx >= thr) { int l = atomicAdd(&s_lc, 1);
            lkey[l] = (((unsigned long long)kx) << 32) | (unsigned)(~(unsigned)(local0 + i)); }
        if (ky >= thr) { int l = atomicAdd(&s_lc, 1);
            lkey[l] = (((unsigned long long)ky) << 32) | (unsigned)(~(unsigned)(local0 + i + 1)); }
        if (kz >= thr) { int l = atomicAdd(&s_lc, 1);
            lkey[l] = (((unsigned long long)kz) << 32) | (unsigned)(~(unsigned)(local0 + i + 2)); }
        if (kw >= thr) { int l = atomicAdd(&s_lc, 1);
            lkey[l] = (((unsigned long long)kw) << 32) | (unsigned)(~(unsigned)(local0 + i + 3)); }
    }
    __syncthreads();
    if (tid == 0) s_base = atomicAdd(&cnt[p], s_lc);
    __syncthreads();
    const int lc = s_lc, base = s_base;
    unsigned long long* cd = cand + (size_t)p * CCAP;
    for (int i = tid; i < lc; i += 256) {
        int pos = base + i;
        if (pos < CCAP) cd[pos] = lkey[i];
    }
}

// ---------------- rank + decode fused: 32-deep LDS batches (MLP), 4 accumulators ------
__global__ __launch_bounds__(256) void rankdec_kernel(
    const unsigned long long* __restrict__ cand, const int* __restrict__ cnt,
    const float* __restrict__ obj_all, const float* __restrict__ deltas,
    const float* __restrict__ anchors,
    float4* __restrict__ cbox, float* __restrict__ csc, float* __restrict__ carea) {
    __shared__ unsigned long long skey[CCAP];
    const int p = blockIdx.x >> 4;
    const int blk = blockIdx.x & 15;
    const int tid = threadIdx.x;
    const int lvl = p % NLVL, img = p / NLVL, k = c_k[lvl];
    int n = cnt[p]; if (n > CCAP) n = CCAP;
    const int i0 = blk << 8;
    if (i0 >= n) return;                       // block-uniform exit, no barrier crossed
    const unsigned long long* cd = cand + (size_t)p * CCAP;
    const int n32 = (n + 31) & ~31;
    for (int i = tid; i < n32; i += 256) skey[i] = (i < n) ? cd[i] : 0ull;
    __syncthreads();
    const int i = i0 + tid;
    const unsigned long long my = (i < n) ? skey[i] : ~0ull;  // sentinel -> rank 0, not emitted
    int r0 = 0, r1 = 0, r2 = 0, r3 = 0;
    for (int j = 0; j < n32; j += 32) {        // 32 wave-uniform LDS reads in flight
        unsigned long long kk[32];
#pragma unroll
        for (int q = 0; q < 32; ++q) kk[q] = skey[j + q];
#pragma unroll
        for (int q = 0; q < 8; ++q) {
            r0 += (int)(kk[q] > my);
            r1 += (int)(kk[8 + q] > my);
            r2 += (int)(kk[16 + q] > my);
            r3 += (int)(kk[24 + q] > my);
        }
    }
    const int rank = (r0 + r1) + (r2 + r3);
    if (i < n && rank < k) {
        unsigned li = ~(unsigned)(my & 0xFFFFFFFFull);
        unsigned idx = (unsigned)c_loff[lvl] + li;
        float o = obj_all[(size_t)img * TOTALN + idx];
        const float4 dd = *(const float4*)(deltas + ((size_t)img * TOTALN + (size_t)idx) * 4);
        const float4 aa = *(const float4*)(anchors + (size_t)idx * 4);
        float a0 = aa.x, a1 = aa.y, a2 = aa.z, a3 = aa.w;
        float w = a2 - a0, h = a3 - a1;
        float cx = a0 + 0.5f * w, cy = a1 + 0.5f * h;
        float dx = dd.x, dy = dd.y;
        float dw = fminf(dd.z, BBOX_CLIP), dh = fminf(dd.w, BBOX_CLIP);
        float pcx = dx * w + cx, pcy = dy * h + cy;
        float pw = expf(dw) * w, ph = expf(dh) * h;
        float bx1 = pcx - 0.5f * pw, by1 = pcy - 0.5f * ph;
        float bx2 = pcx + 0.5f * pw, by2 = pcy + 0.5f * ph;
        float x1 = fminf(fmaxf(bx1, 0.f), IMGSZ);
        float y1 = fminf(fmaxf(by1, 0.f), IMGSZ);
        float x2 = fminf(fmaxf(bx2, 0.f), IMGSZ);
        float y2 = fminf(fmaxf(by2, 0.f), IMGSZ);
        float wsz = x2 - x1, hsz = y2 - y1;
        float scv = (wsz >= MINSZ && hsz >= MINSZ) ? 1.0f / (1.0f + expf(-o)) : 0.0f;
        cbox[(size_t)p * CAP + rank] = make_float4(x1, y1, x2, y2);
        csc[(size_t)p * CAP + rank] = scv;
        carea[(size_t)p * CAP + rank] = wsz * hsz;   // same expression the mask used
    }
}

// ---------------- NMS phase 1: ballot-form mask, wave = one (word, 64-row chunk) -------
__global__ __launch_bounds__(256) void mask_kernel(const float4* __restrict__ cbox,
                                                   const float* __restrict__ carea,
                                                   unsigned long long* __restrict__ gmaskT,
                                                   unsigned long long* __restrict__ tdiag) {
    const int bid = blockIdx.x;
    const int p = bid / 34;
    const int wid = __builtin_amdgcn_readfirstlane(threadIdx.x >> 6);
    const int lane = threadIdx.x & 63;
    const int q = (bid - p * 34) * 4 + wid;           // 0..135, SGPR
    const int w = c_pw[q], rc = c_pr[q];              // SGPR via scalar loads
    const int base = p * CAP;

    const float4 cb = cbox[base + (w << 6) + lane];   // column box, per-lane registers
    const float car = carea[base + (w << 6) + lane];
    const float4* rowb = cbox + base + (rc << 6);     // wave-uniform row pointers
    const float* rowa = carea + base + (rc << 6);

    unsigned long long tbits = 0, myword = 0;
    const bool isdiag = (rc == w);                    // wave-uniform
#pragma unroll 8
    for (int r = 0; r < 64; ++r) {
        const float4 rb = rowb[r];                    // s_load_dwordx4 (uniform)
        const float ar = rowa[r];                     // s_load_dword  (uniform)
        float ltx = fmaxf(rb.x, cb.x), lty = fmaxf(rb.y, cb.y);
        float rbx = fminf(rb.z, cb.z), rby = fminf(rb.w, cb.w);
        float wx = fmaxf(rbx - ltx, 0.f), wy = fmaxf(rby - lty, 0.f);
        float inter = wx * wy;
        float un = (ar + car) - inter;
        bool sup = (un > 0.f) && ((double)inter >= M_TH * (double)un);
        unsigned long long bits = __ballot(sup);
        if (isdiag) {
            bits &= (0xFFFFFFFFFFFFFFFEull << r);     // keep col > row within the chunk
            if (sup && lane > r) tbits |= (1ull << r);
        }
        myword = (lane == r) ? bits : myword;
    }
    gmaskT[((size_t)p << 14) + ((size_t)w << 10) + (rc << 6) + lane] = myword;
    if (isdiag) tdiag[((size_t)p << 10) + (w << 6) + lane] = tbits;
}

// ---------------- NMS phase 2: bulk mask->LDS + word-level fixpoint greedy scan --------
__global__ __launch_bounds__(1024) void scan_kernel(
    const unsigned long long* __restrict__ gmaskT,
    const unsigned long long* __restrict__ tdiag,
    const float4* __restrict__ cbox, const float* __restrict__ csc,
    float* __restrict__ svbox, float* __restrict__ svsc, int* __restrict__ svcnt) {
    __shared__ unsigned long long lm[CAP * LMS];
    __shared__ float ssc[CAP];
    __shared__ unsigned short survL[CAP];
    __shared__ int s_ns;
    const int p = blockIdx.x, tid = threadIdx.x;
    const int lvl = p % NLVL, k = c_k[lvl];
    const int base = p * CAP;

    {   // copy transposed mask -> LDS[row*17 + w] (coalesced reads; 17-stride de-bank)
        const ulonglong2* g2 = (const ulonglong2*)(gmaskT + ((size_t)p << 14));
#pragma unroll
        for (int c = 0; c < 8; ++c) {
            ulonglong2 v = g2[c * 1024 + tid];
            const int e = (c * 1024 + tid) << 1;      // u64 index = w*1024 + row
            const int w = e >> 10, row = e & 1023;
            lm[row * LMS + w] = v.x;
            lm[(row + 1) * LMS + w] = v.y;
        }
        ssc[tid] = (tid < k) ? csc[base + tid] : 0.f;  // k-guard: no csc memset needed
    }
    __syncthreads();

    if (tid < 64) {
        const int lane = tid;
        const unsigned long long* td = tdiag + ((size_t)p << 10);
        unsigned long long tg = td[lane];             // group 0 transposed diagonal
        const unsigned long long mybit = 1ull << lane;
        const unsigned long long below = mybit - 1ull;
        int ns = 0;
        for (int g = 0; g < 16; ++g) {
            unsigned long long tgn = (g < 15) ? td[((g + 1) << 6) + lane] : 0ull;
            unsigned long long wv = __ballot(ssc[(g << 6) + lane] <= 0.f);
            // cross-group suppression: OR word g over all prior accepts (off-chain MLP)
            unsigned long long a0 = 0, a1 = 0, a2 = 0, a3 = 0;
            int j = lane;
            for (; j + 192 < ns; j += 256) {
                int r0 = survL[j], r1 = survL[j + 64];
                int r2 = survL[j + 128], r3 = survL[j + 192];
                a0 |= lm[r0 * LMS + g];
                a1 |= lm[r1 * LMS + g];
                a2 |= lm[r2 * LMS + g];
                a3 |= lm[r3 * LMS + g];
            }
            for (; j < ns; j += 64) a0 |= lm[((int)survL[j]) * LMS + g];
            unsigned long long accw = (a0 | a1) | (a2 | a3);
#pragma unroll
            for (int d2 = 1; d2 < 64; d2 <<= 1)
                accw |= (unsigned long long)__shfl_xor((unsigned long long)accw, d2);

            const unsigned long long alive = ~(wv | accw);
            unsigned long long A = alive;
#pragma unroll 1
            for (int it = 0; it < 64; ++it) {      // fixpoint -> exact greedy set
                bool kill = (tg & A) != 0ull;
                unsigned long long An = alive & ~__ballot(kill);
                if (An == A) break;
                A = An;
            }
            if (A & mybit)                          // parallel, order-preserving emission
                survL[ns + __popcll(A & below)] = (unsigned short)((g << 6) + lane);
            ns += __popcll(A);
            tg = tgn;
        }
        if (lane == 0) s_ns = ns;
    }
    __syncthreads();

    const int ns = s_ns;
    for (int s = tid; s < ns; s += 1024) {
        int r = survL[s];
        svsc[base + s] = ssc[r];
        *(float4*)(svbox + ((size_t)(base + s)) * 4) = cbox[base + r];
    }
    if (tid == 0) svcnt[p] = ns;
}

// ---------------- merge: 80 blocks (img,level); branchless bit-descent rank ----------
__global__ __launch_bounds__(256) void merge_kernel(
    const float* __restrict__ svbox, const float* __restrict__ svsc,
    const int* __restrict__ svcnt, float* __restrict__ out) {
    __shared__ float sls[NLVL][CAP];
    __shared__ int scnt[NLVL];
    const int img = blockIdx.x / NLVL, l = blockIdx.x % NLVL;
    const int tid = threadIdx.x;
    if (tid < NLVL) scnt[tid] = svcnt[img * NLVL + tid];
    __syncthreads();
    for (int m = 0; m < NLVL; ++m) {
        int c = scnt[m];
        for (int i = tid; i < c; i += 256) sls[m][i] = svsc[(img * NLVL + m) * CAP + i];
    }
    __syncthreads();
    const int c = scnt[l];
    for (int i = tid; i < c; i += 256) {
        const float s = sls[l][i];
        int pos = i;
#pragma unroll
        for (int m = 0; m < NLVL; ++m) {
            if (m == l) continue;
            const int n2 = scnt[m];
            int lo = 0;
#pragma unroll
            for (int st = 512; st > 0; st >>= 1) {
                const int idx = lo + st;
                const bool ok = (idx <= n2);
                const float v = sls[m][ok ? idx - 1 : 0];   // in-bounds; unused if !ok
                const bool ahead = (m < l) ? (v >= s) : (v > s);
                if (ok && ahead) lo = idx;
            }
            pos += lo;
        }
        if (pos < POST_N) {
            const int src = (img * NLVL + l) * CAP + i;
            float* o = out + ((size_t)img * POST_N + pos) * 5;
            o[0] = svbox[(size_t)src * 4 + 0];
            o[1] = svbox[(size_t)src * 4 + 1];
            o[2] = svbox[(size_t)src * 4 + 2];
            o[3] = svbox[(size_t)src * 4 + 3];
            o[4] = s;
        }
    }
}

extern "C" void kernel_launch(void* const* d_in, const int* in_sizes, int n_in,
                              void* d_out, int out_size, void* d_ws, size_t ws_size,
                              hipStream_t stream) {
    const float* obj     = (const float*)d_in[0];
    const float* deltas  = (const float*)d_in[1];
    const float* anchors = (const float*)d_in[2];
    float* out = (float*)d_out;

    char* w = (char*)d_ws;
    size_t off = 0;
    auto alloc = [&](size_t bytes) -> void* {
        void* pp = w + off;
        off += (bytes + 511) & ~(size_t)511;
        return pp;
    };
    // zeroed region: ghist + donecnt + ccnt cleared with ONE memset
    size_t z0 = off;
    unsigned* ghist   = (unsigned*)alloc((size_t)NPROB * HBINS * 4);
    int*      donecnt = (int*)alloc((size_t)NPROB * 4);
    int*      ccnt    = (int*)alloc((size_t)NPROB * 4);
    size_t zspan = off - z0;
    unsigned* b1buf = (unsigned*)alloc((size_t)NPROB * 4);
    unsigned long long* cand = (unsigned long long*)alloc((size_t)NPROB * CCAP * 8);
    float4*   cbox  = (float4*)alloc((size_t)NPROB * CAP * 16);
    float*    csc   = (float*)alloc((size_t)NPROB * CAP * 4);
    float*    carea = (float*)alloc((size_t)NPROB * CAP * 4);
    unsigned long long* gmaskT = (unsigned long long*)alloc((size_t)NPROB * CAP * 16 * 8);
    unsigned long long* tdiag = (unsigned long long*)alloc((size_t)NPROB * CAP * 8);
    float* svbox = (float*)alloc((size_t)NPROB * CAP * 16);
    float* svsc  = (float*)alloc((size_t)NPROB * CAP * 4);
    int*   svcnt = (int*)alloc((size_t)NPROB * 4);
    if (off > ws_size) return;  // fail cleanly (output stays poisoned -> visible failure)

    hipMemsetAsync(ghist, 0, zspan, stream);
    hipMemsetAsync(d_out, 0, (size_t)out_size * sizeof(float), stream);

    hist_kernel<<<NBATCH * NBLK, 256, 0, stream>>>(obj, ghist, donecnt, b1buf);
    compact_kernel<<<NBATCH * NBLK, 256, 0, stream>>>(obj, b1buf, ccnt, cand);
    rankdec_kernel<<<NPROB * 16, 256, 0, stream>>>(cand, ccnt, obj, deltas, anchors,
                                                   cbox, csc, carea);
    mask_kernel<<<NPROB * 34, 256, 0, stream>>>(cbox, carea, gmaskT, tdiag);
    scan_kernel<<<NPROB, 1024, 0, stream>>>(gmaskT, tdiag, cbox, csc, svbox, svsc, svcnt);
    merge_kernel<<<NPROB, 256, 0, stream>>>(svbox, svsc, svcnt, out);
}

// Round 20
// 138.634 us; speedup vs baseline: 1.3403x; 1.0142x over previous
//
#include <hip/hip_runtime.h>
#include <math.h>

#pragma clang fp contract(off)

#define NLVL 5
#define TOTALN 261888
#define NBATCH 16
#define CAP 1024
#define NPROB (NBATCH * NLVL)
#define POST_N 1000
#define NMS_TH 0.7f
#define MINSZ 1e-3f
#define IMGSZ 1024.0f
#define BBOX_CLIP 4.135166556742356f

// exact midpoint between 0.7f and nextafterf(0.7f): fl32(a/b) > 0.7f  <=>  a >= M_TH*b (b>0)
// (0.7f mantissa odd -> round-to-nearest-even sends the tie upward -> ">="); 25-bit M_TH
// times 24-bit un is exact in double, and (double)inter is exact -> predicate is exact.
#define M_TH 0x1.666667p-1

#define HBINS 2048
#define CCAP 4096
#define NBLK 65      // hist/compact blocks per image (48+12+3+1+1)
#define NPAIR 136    // (w, rc<=w) wave-pairs per problem; 34 blocks x 4 waves

__constant__ int c_loff[NLVL] = {0, 196608, 245760, 258048, 261120};
__constant__ int c_k[NLVL]    = {1000, 1000, 1000, 1000, 768};
__constant__ int c_nch[NLVL]  = {48, 12, 3, 1, 1};     // hist/compact blocks per level

// pair q -> (word w, row-chunk rc), rc <= w, q = w(w+1)/2 + rc
__constant__ unsigned char c_pw[NPAIR] = {
    0, 1,1, 2,2,2, 3,3,3,3, 4,4,4,4,4, 5,5,5,5,5,5, 6,6,6,6,6,6,6,
    7,7,7,7,7,7,7,7, 8,8,8,8,8,8,8,8,8, 9,9,9,9,9,9,9,9,9,9,
    10,10,10,10,10,10,10,10,10,10,10, 11,11,11,11,11,11,11,11,11,11,11,11,
    12,12,12,12,12,12,12,12,12,12,12,12,12, 13,13,13,13,13,13,13,13,13,13,13,13,13,13,
    14,14,14,14,14,14,14,14,14,14,14,14,14,14,14,
    15,15,15,15,15,15,15,15,15,15,15,15,15,15,15,15};
__constant__ unsigned char c_pr[NPAIR] = {
    0, 0,1, 0,1,2, 0,1,2,3, 0,1,2,3,4, 0,1,2,3,4,5, 0,1,2,3,4,5,6,
    0,1,2,3,4,5,6,7, 0,1,2,3,4,5,6,7,8, 0,1,2,3,4,5,6,7,8,9,
    0,1,2,3,4,5,6,7,8,9,10, 0,1,2,3,4,5,6,7,8,9,10,11,
    0,1,2,3,4,5,6,7,8,9,10,11,12, 0,1,2,3,4,5,6,7,8,9,10,11,12,13,
    0,1,2,3,4,5,6,7,8,9,10,11,12,13,14,
    0,1,2,3,4,5,6,7,8,9,10,11,12,13,14,15};

__device__ __forceinline__ unsigned monokey(float f) {
    unsigned b = __float_as_uint(f);
    return (b & 0x80000000u) ? ~b : (b | 0x80000000u);
}

// block b in [0,NBLK) -> (lvl, start, cnt); spans never straddle levels
__device__ __forceinline__ void blk_span(int b, int& lvl, int& start, int& cnt) {
    if (b < 48)      { lvl = 0; start = b * 4096;                  cnt = 4096; }
    else if (b < 60) { lvl = 1; start = 196608 + (b - 48) * 4096;  cnt = 4096; }
    else if (b < 63) { lvl = 2; start = 245760 + (b - 60) * 4096;  cnt = 4096; }
    else if (b == 63){ lvl = 3; start = 258048;                    cnt = 3072; }
    else             { lvl = 4; start = 261120;                    cnt = 768;  }
}

// ---------------- pass 1: 4096-elem float4 histogram + fused last-block pick ----------
__global__ __launch_bounds__(256) void hist_kernel(const float* __restrict__ obj_all,
                                                   unsigned* __restrict__ ghist,
                                                   int* __restrict__ donecnt,
                                                   unsigned* __restrict__ b1out) {
    __shared__ unsigned lh[HBINS];
    __shared__ int s_last;
    const int tid = threadIdx.x;
    const int img = blockIdx.x / NBLK, b = blockIdx.x - img * NBLK;
    int lvl, start, cnt;
    blk_span(b, lvl, start, cnt);
    const int p = img * NLVL + lvl;
    for (int i = tid; i < HBINS; i += 256) lh[i] = 0;
    __syncthreads();
    const float* o = obj_all + (size_t)img * TOTALN + start;
    for (int i = tid * 4; i < cnt; i += 1024) {        // float4: 16B/lane coalesced
        float4 v = *(const float4*)(o + i);
        atomicAdd(&lh[monokey(v.x) >> 21], 1u);
        atomicAdd(&lh[monokey(v.y) >> 21], 1u);
        atomicAdd(&lh[monokey(v.z) >> 21], 1u);
        atomicAdd(&lh[monokey(v.w) >> 21], 1u);
    }
    __syncthreads();
    unsigned* gh = ghist + (size_t)p * HBINS;
    for (int i = tid; i < HBINS; i += 256) {
        unsigned v = lh[i];
        if (v) atomicAdd(&gh[i], v);
    }
    __syncthreads();   // barrier drains vmcnt -> this block's ghist atomics are complete
    if (tid == 0) s_last = (atomicAdd(&donecnt[p], 1) == c_nch[lvl] - 1) ? 1 : 0;
    __syncthreads();
    if (!s_last) return;

    // last block for problem p: coherent re-read + suffix-sum threshold pick
    for (int i = tid; i < HBINS; i += 256) lh[i] = atomicAdd(&gh[i], 0u);
    __syncthreads();
    const int k = c_k[lvl];
    for (int d = 1; d < HBINS; d <<= 1) {
        unsigned v[HBINS / 256];
#pragma unroll
        for (int r = 0; r < HBINS / 256; ++r) {
            int i = tid + r * 256;
            v[r] = lh[i] + ((i + d < HBINS) ? lh[i + d] : 0u);
        }
        __syncthreads();
#pragma unroll
        for (int r = 0; r < HBINS / 256; ++r) lh[tid + r * 256] = v[r];
        __syncthreads();
    }
#pragma unroll
    for (int r = 0; r < HBINS / 256; ++r) {
        int i = tid + r * 256;
        if (lh[i] >= (unsigned)k && (i == HBINS - 1 || lh[i + 1] < (unsigned)k))
            b1out[p] = (unsigned)i;
    }
}

// ---------------- pass 2: compact all keys >= (b1<<21), 4096-elem float4 blocks -------
__global__ __launch_bounds__(256) void compact_kernel(const float* __restrict__ obj_all,
                                                      const unsigned* __restrict__ b1in,
                                                      int* __restrict__ cnt,
                                                      unsigned long long* __restrict__ cand) {
    __shared__ unsigned long long lkey[4096];
    __shared__ int s_lc, s_base;
    const int tid = threadIdx.x;
    const int img = blockIdx.x / NBLK, b = blockIdx.x - img * NBLK;
    int lvl, start, nrem;
    blk_span(b, lvl, start, nrem);
    const int p = img * NLVL + lvl;
    const unsigned thr = b1in[p] << 21;
    const int local0 = start - c_loff[lvl];
    if (tid == 0) s_lc = 0;
    __syncthreads();
    const float* o = obj_all + (size_t)img * TOTALN + start;
    for (int i = tid * 4; i < nrem; i += 1024) {
        float4 v = *(const float4*)(o + i);
        unsigned kx = monokey(v.x), ky = monokey(v.y);
        unsigned kz = monokey(v.z), kw = monokey(v.w);
        if (kx >= thr) { int l = atomicAdd(&s_lc, 1);
            lkey[l] = (((unsigned long long)kx) << 32) | (unsigned)(~(unsigned)(local0 + i)); }
        if (ky >= thr) { int l = atomicAdd(&s_lc, 1);
            lkey[l] = (((unsigned long long)ky) << 32) | (unsigned)(~(unsigned)(local0 + i + 1)); }
        if (kz >= thr) { int l = atomicAdd(&s_lc, 1);
            lkey[l] = (((unsigned long long)kz) << 32) | (unsigned)(~(unsigned)(local0 + i + 2)); }
        if (kw >= thr) { int l = atomicAdd(&s_lc, 1);
            lkey[l] = (((unsigned long long)kw) << 32) | (unsigned)(~(unsigned)(local0 + i + 3)); }
    }
    __syncthreads();
    if (tid == 0) s_base = atomicAdd(&cnt[p], s_lc);
    __syncthreads();
    const int lc = s_lc, base = s_base;
    unsigned long long* cd = cand + (size_t)p * CCAP;
    for (int i = tid; i < lc; i += 256) {
        int pos = base + i;
        if (pos < CCAP) cd[pos] = lkey[i];
    }
}

// ---------------- rank + decode fused: 32-deep LDS batches (MLP), 4 accumulators ------
__global__ __launch_bounds__(256) void rankdec_kernel(
    const unsigned long long* __restrict__ cand, const int* __restrict__ cnt,
    const float* __restrict__ obj_all, const float* __restrict__ deltas,
    const float* __restrict__ anchors,
    float4* __restrict__ cbox, float* __restrict__ csc, float* __restrict__ carea) {
    __shared__ unsigned long long skey[CCAP];
    const int p = blockIdx.x >> 4;
    const int blk = blockIdx.x & 15;
    const int tid = threadIdx.x;
    const int lvl = p % NLVL, img = p / NLVL, k = c_k[lvl];
    int n = cnt[p]; if (n > CCAP) n = CCAP;
    const int i0 = blk << 8;
    if (i0 >= n) return;                       // block-uniform exit, no barrier crossed
    const unsigned long long* cd = cand + (size_t)p * CCAP;
    const int n32 = (n + 31) & ~31;
    for (int i = tid; i < n32; i += 256) skey[i] = (i < n) ? cd[i] : 0ull;
    __syncthreads();
    const int i = i0 + tid;
    const unsigned long long my = (i < n) ? skey[i] : ~0ull;  // sentinel -> rank 0, not emitted
    int r0 = 0, r1 = 0, r2 = 0, r3 = 0;
    for (int j = 0; j < n32; j += 32) {        // 32 wave-uniform LDS reads in flight
        unsigned long long kk[32];
#pragma unroll
        for (int q = 0; q < 32; ++q) kk[q] = skey[j + q];
#pragma unroll
        for (int q = 0; q < 8; ++q) {
            r0 += (int)(kk[q] > my);
            r1 += (int)(kk[8 + q] > my);
            r2 += (int)(kk[16 + q] > my);
            r3 += (int)(kk[24 + q] > my);
        }
    }
    const int rank = (r0 + r1) + (r2 + r3);
    if (i < n && rank < k) {
        unsigned li = ~(unsigned)(my & 0xFFFFFFFFull);
        unsigned idx = (unsigned)c_loff[lvl] + li;
        float o = obj_all[(size_t)img * TOTALN + idx];
        const float4 dd = *(const float4*)(deltas + ((size_t)img * TOTALN + (size_t)idx) * 4);
        const float4 aa = *(const float4*)(anchors + (size_t)idx * 4);
        float a0 = aa.x, a1 = aa.y, a2 = aa.z, a3 = aa.w;
        float w = a2 - a0, h = a3 - a1;
        float cx = a0 + 0.5f * w, cy = a1 + 0.5f * h;
        float dx = dd.x, dy = dd.y;
        float dw = fminf(dd.z, BBOX_CLIP), dh = fminf(dd.w, BBOX_CLIP);
        float pcx = dx * w + cx, pcy = dy * h + cy;
        float pw = expf(dw) * w, ph = expf(dh) * h;
        float bx1 = pcx - 0.5f * pw, by1 = pcy - 0.5f * ph;
        float bx2 = pcx + 0.5f * pw, by2 = pcy + 0.5f * ph;
        float x1 = fminf(fmaxf(bx1, 0.f), IMGSZ);
        float y1 = fminf(fmaxf(by1, 0.f), IMGSZ);
        float x2 = fminf(fmaxf(bx2, 0.f), IMGSZ);
        float y2 = fminf(fmaxf(by2, 0.f), IMGSZ);
        float wsz = x2 - x1, hsz = y2 - y1;
        float scv = (wsz >= MINSZ && hsz >= MINSZ) ? 1.0f / (1.0f + expf(-o)) : 0.0f;
        cbox[(size_t)p * CAP + rank] = make_float4(x1, y1, x2, y2);
        csc[(size_t)p * CAP + rank] = scv;
        carea[(size_t)p * CAP + rank] = wsz * hsz;   // same expression the mask used
    }
}

// ---------------- NMS phase 1: suppressed-by mask S[rc][col] ----------------
// Wave (w, rc): lane = col 64w+lane. sbits bit r = (row rc*64+r suppresses col).
// Lane accumulates its OWN column's bits -> no ballot, no row-word select. Diagonal
// strictness (col > row) is one final &below(lane). Store gmaskS[p][rc][col]:
// lanes consecutive -> one coalesced 512B store. No separate tdiag (diag = S[g][col]).
// Words rc > col/64 never written (scan reads only rc <= g).
__global__ __launch_bounds__(256) void mask_kernel(const float4* __restrict__ cbox,
                                                   const float* __restrict__ carea,
                                                   unsigned long long* __restrict__ gmaskS) {
    const int bid = blockIdx.x;
    const int p = bid / 34;
    const int wid = __builtin_amdgcn_readfirstlane(threadIdx.x >> 6);
    const int lane = threadIdx.x & 63;
    const int q = (bid - p * 34) * 4 + wid;           // 0..135, SGPR
    const int w = c_pw[q], rc = c_pr[q];              // SGPR via scalar loads
    const int base = p * CAP;

    const float4 cb = cbox[base + (w << 6) + lane];   // column box, per-lane registers
    const float car = carea[base + (w << 6) + lane];
    const float4* rowb = cbox + base + (rc << 6);     // wave-uniform row pointers
    const float* rowa = carea + base + (rc << 6);

    unsigned slo = 0, shi = 0;
#pragma unroll 8
    for (int r = 0; r < 64; ++r) {
        const float4 rb = rowb[r];                    // s_load_dwordx4 (uniform)
        const float ar = rowa[r];                     // s_load_dword  (uniform)
        float ltx = fmaxf(rb.x, cb.x), lty = fmaxf(rb.y, cb.y);
        float rbx = fminf(rb.z, cb.z), rby = fminf(rb.w, cb.w);
        float wx = fmaxf(rbx - ltx, 0.f), wy = fmaxf(rby - lty, 0.f);
        float inter = wx * wy;
        float un = (ar + car) - inter;
        bool sup = (un > 0.f) && ((double)inter >= M_TH * (double)un);
        if (r < 32) slo |= sup ? (1u << r) : 0u;
        else        shi |= sup ? (1u << (r - 32)) : 0u;
    }
    unsigned long long sbits = (((unsigned long long)shi) << 32) | slo;
    if (rc == w) sbits &= ((1ull << lane) - 1ull);    // diag: strictly lower rows only
    gmaskS[(((size_t)(p * 16 + rc)) << 10) + (w << 6) + lane] = sbits;
}

// ---------------- NMS phase 2: register greedy scan, no LDS mask copy -----------------
// Lane = column of current group. killed_c = OR_{w<g}(S[w][c] & A[w]) with accepted sets
// A[w] in (uniform) registers; fully-unrolled g-loop keeps kk[]/aw[] statically indexed.
// Per group: <=g+1 coalesced 512B loads + ~g u64 AND/ORs + the usual diag fixpoint.
__global__ __launch_bounds__(256) void scan_kernel(
    const unsigned long long* __restrict__ gmaskS,
    const float4* __restrict__ cbox, const float* __restrict__ csc,
    float* __restrict__ svbox, float* __restrict__ svsc, int* __restrict__ svcnt) {
    __shared__ float ssc[CAP];
    __shared__ unsigned short survL[CAP];
    __shared__ int s_ns;
    const int p = blockIdx.x, tid = threadIdx.x;
    const int lvl = p % NLVL, k = c_k[lvl];
    const int base = p * CAP;
    for (int i = tid; i < CAP; i += 256) ssc[i] = (i < k) ? csc[base + i] : 0.f;
    __syncthreads();

    if (tid < 64) {
        const int lane = tid;
        const unsigned long long mybit = 1ull << lane;
        const unsigned long long below = mybit - 1ull;
        const unsigned long long* gS = gmaskS + ((size_t)p << 14);   // p*16*1024
        unsigned long long aw[16];
        int ns = 0;
#pragma unroll
        for (int g = 0; g < 16; ++g) {
            unsigned long long kk[16];
#pragma unroll
            for (int rc = 0; rc <= g; ++rc)                  // coalesced 512B each
                kk[rc] = gS[(((size_t)rc) << 10) + (g << 6) + lane];
            unsigned long long wv = __ballot(ssc[(g << 6) + lane] <= 0.f);
            unsigned long long killed = 0;
#pragma unroll
            for (int w2 = 0; w2 < g; ++w2) killed |= kk[w2] & aw[w2];
            const unsigned long long kmask = __ballot(killed != 0ull);
            const unsigned long long alive = ~(wv | kmask);
            const unsigned long long dg = kk[g];             // strict-lower diag word
            unsigned long long A = alive;
#pragma unroll 1
            for (int it = 0; it < 64; ++it) {                // fixpoint -> exact greedy
                bool kill = (dg & A) != 0ull;
                unsigned long long An = alive & ~__ballot(kill);
                if (An == A) break;
                A = An;
            }
            if (A & mybit)                                   // parallel, ordered emission
                survL[ns + __popcll(A & below)] = (unsigned short)((g << 6) + lane);
            ns += __popcll(A);
            aw[g] = A;
        }
        if (lane == 0) s_ns = ns;
    }
    __syncthreads();

    const int ns = s_ns;
    for (int s = tid; s < ns; s += 256) {
        int r = survL[s];
        svsc[base + s] = ssc[r];
        *(float4*)(svbox + ((size_t)(base + s)) * 4) = cbox[base + r];
    }
    if (tid == 0) svcnt[p] = ns;
}

// ---------------- merge: 80 blocks (img,level); branchless bit-descent rank ----------
__global__ __launch_bounds__(256) void merge_kernel(
    const float* __restrict__ svbox, const float* __restrict__ svsc,
    const int* __restrict__ svcnt, float* __restrict__ out) {
    __shared__ float sls[NLVL][CAP];
    __shared__ int scnt[NLVL];
    const int img = blockIdx.x / NLVL, l = blockIdx.x % NLVL;
    const int tid = threadIdx.x;
    if (tid < NLVL) scnt[tid] = svcnt[img * NLVL + tid];
    __syncthreads();
    for (int m = 0; m < NLVL; ++m) {
        int c = scnt[m];
        for (int i = tid; i < c; i += 256) sls[m][i] = svsc[(img * NLVL + m) * CAP + i];
    }
    __syncthreads();
    const int c = scnt[l];
    for (int i = tid; i < c; i += 256) {
        const float s = sls[l][i];
        int pos = i;
#pragma unroll
        for (int m = 0; m < NLVL; ++m) {
            if (m == l) continue;
            const int n2 = scnt[m];
            int lo = 0;
#pragma unroll
            for (int st = 512; st > 0; st >>= 1) {
                const int idx = lo + st;
                const bool ok = (idx <= n2);
                const float v = sls[m][ok ? idx - 1 : 0];   // in-bounds; unused if !ok
                const bool ahead = (m < l) ? (v >= s) : (v > s);
                if (ok && ahead) lo = idx;
            }
            pos += lo;
        }
        if (pos < POST_N) {
            const int src = (img * NLVL + l) * CAP + i;
            float* o = out + ((size_t)img * POST_N + pos) * 5;
            o[0] = svbox[(size_t)src * 4 + 0];
            o[1] = svbox[(size_t)src * 4 + 1];
            o[2] = svbox[(size_t)src * 4 + 2];
            o[3] = svbox[(size_t)src * 4 + 3];
            o[4] = s;
        }
    }
}

extern "C" void kernel_launch(void* const* d_in, const int* in_sizes, int n_in,
                              void* d_out, int out_size, void* d_ws, size_t ws_size,
                              hipStream_t stream) {
    const float* obj     = (const float*)d_in[0];
    const float* deltas  = (const float*)d_in[1];
    const float* anchors = (const float*)d_in[2];
    float* out = (float*)d_out;

    char* w = (char*)d_ws;
    size_t off = 0;
    auto alloc = [&](size_t bytes) -> void* {
        void* pp = w + off;
        off += (bytes + 511) & ~(size_t)511;
        return pp;
    };
    // zeroed region: ghist + donecnt + ccnt cleared with ONE memset
    size_t z0 = off;
    unsigned* ghist   = (unsigned*)alloc((size_t)NPROB * HBINS * 4);
    int*      donecnt = (int*)alloc((size_t)NPROB * 4);
    int*      ccnt    = (int*)alloc((size_t)NPROB * 4);
    size_t zspan = off - z0;
    unsigned* b1buf = (unsigned*)alloc((size_t)NPROB * 4);
    unsigned long long* cand = (unsigned long long*)alloc((size_t)NPROB * CCAP * 8);
    float4*   cbox  = (float4*)alloc((size_t)NPROB * CAP * 16);
    float*    csc   = (float*)alloc((size_t)NPROB * CAP * 4);
    float*    carea = (float*)alloc((size_t)NPROB * CAP * 4);
    unsigned long long* gmaskS = (unsigned long long*)alloc((size_t)NPROB * 16 * CAP * 8);
    float* svbox = (float*)alloc((size_t)NPROB * CAP * 16);
    float* svsc  = (float*)alloc((size_t)NPROB * CAP * 4);
    int*   svcnt = (int*)alloc((size_t)NPROB * 4);
    if (off > ws_size) return;  // fail cleanly (output stays poisoned -> visible failure)

    hipMemsetAsync(ghist, 0, zspan, stream);
    hipMemsetAsync(d_out, 0, (size_t)out_size * sizeof(float), stream);

    hist_kernel<<<NBATCH * NBLK, 256, 0, stream>>>(obj, ghist, donecnt, b1buf);
    compact_kernel<<<NBATCH * NBLK, 256, 0, stream>>>(obj, b1buf, ccnt, cand);
    rankdec_kernel<<<NPROB * 16, 256, 0, stream>>>(cand, ccnt, obj, deltas, anchors,
                                                   cbox, csc, carea);
    mask_kernel<<<NPROB * 34, 256, 0, stream>>>(cbox, carea, gmaskS);
    scan_kernel<<<NPROB, 256, 0, stream>>>(gmaskS, cbox, csc, svbox, svsc, svcnt);
    merge_kernel<<<NPROB, 256, 0, stream>>>(svbox, svsc, svcnt, out);
}

// Round 21
// 135.830 us; speedup vs baseline: 1.3680x; 1.0206x over previous
//
#include <hip/hip_runtime.h>
#include <math.h>

#pragma clang fp contract(off)

#define NLVL 5
#define TOTALN 261888
#define NBATCH 16
#define CAP 1024
#define NPROB (NBATCH * NLVL)
#define POST_N 1000
#define NMS_TH 0.7f
#define MINSZ 1e-3f
#define IMGSZ 1024.0f
#define BBOX_CLIP 4.135166556742356f

// exact midpoint between 0.7f and nextafterf(0.7f): fl32(a/b) > 0.7f  <=>  a >= M_TH*b (b>0)
// (0.7f mantissa odd -> round-to-nearest-even sends the tie upward -> ">="); 25-bit M_TH
// times 24-bit un is exact in double, and (double)inter is exact -> predicate is exact.
#define M_TH 0x1.666667p-1

#define HBINS 2048
#define CCAP 4096
#define NBLK 65      // hist/compact blocks per image (48+12+3+1+1)
#define NPAIR 136    // (w, rc<=w) wave-pairs per problem; 34 blocks x 4 waves

__constant__ int c_loff[NLVL] = {0, 196608, 245760, 258048, 261120};
__constant__ int c_k[NLVL]    = {1000, 1000, 1000, 1000, 768};
__constant__ int c_nch[NLVL]  = {48, 12, 3, 1, 1};     // hist/compact blocks per level

// pair q -> (word w, row-chunk rc), rc <= w, q = w(w+1)/2 + rc
__constant__ unsigned char c_pw[NPAIR] = {
    0, 1,1, 2,2,2, 3,3,3,3, 4,4,4,4,4, 5,5,5,5,5,5, 6,6,6,6,6,6,6,
    7,7,7,7,7,7,7,7, 8,8,8,8,8,8,8,8,8, 9,9,9,9,9,9,9,9,9,9,
    10,10,10,10,10,10,10,10,10,10,10, 11,11,11,11,11,11,11,11,11,11,11,11,
    12,12,12,12,12,12,12,12,12,12,12,12,12, 13,13,13,13,13,13,13,13,13,13,13,13,13,13,
    14,14,14,14,14,14,14,14,14,14,14,14,14,14,14,
    15,15,15,15,15,15,15,15,15,15,15,15,15,15,15,15};
__constant__ unsigned char c_pr[NPAIR] = {
    0, 0,1, 0,1,2, 0,1,2,3, 0,1,2,3,4, 0,1,2,3,4,5, 0,1,2,3,4,5,6,
    0,1,2,3,4,5,6,7, 0,1,2,3,4,5,6,7,8, 0,1,2,3,4,5,6,7,8,9,
    0,1,2,3,4,5,6,7,8,9,10, 0,1,2,3,4,5,6,7,8,9,10,11,
    0,1,2,3,4,5,6,7,8,9,10,11,12, 0,1,2,3,4,5,6,7,8,9,10,11,12,13,
    0,1,2,3,4,5,6,7,8,9,10,11,12,13,14,
    0,1,2,3,4,5,6,7,8,9,10,11,12,13,14,15};

__device__ __forceinline__ unsigned monokey(float f) {
    unsigned b = __float_as_uint(f);
    return (b & 0x80000000u) ? ~b : (b | 0x80000000u);
}

// block b in [0,NBLK) -> (lvl, start, cnt); spans never straddle levels
__device__ __forceinline__ void blk_span(int b, int& lvl, int& start, int& cnt) {
    if (b < 48)      { lvl = 0; start = b * 4096;                  cnt = 4096; }
    else if (b < 60) { lvl = 1; start = 196608 + (b - 48) * 4096;  cnt = 4096; }
    else if (b < 63) { lvl = 2; start = 245760 + (b - 60) * 4096;  cnt = 4096; }
    else if (b == 63){ lvl = 3; start = 258048;                    cnt = 3072; }
    else             { lvl = 4; start = 261120;                    cnt = 768;  }
}

// ---------------- custom zero (the runtime's small fillBuffer kernel costs ~40us) ------
__global__ __launch_bounds__(256) void zero_kernel(ulonglong2* __restrict__ a, int na,
                                                   ulonglong2* __restrict__ b, int nb) {
    const int i = blockIdx.x * 256 + threadIdx.x;
    const ulonglong2 z = make_ulonglong2(0ull, 0ull);
    if (i < na) a[i] = z;
    if (i < nb) b[i] = z;
}

// ---------------- pass 1: 4096-elem float4 histogram + fused last-block pick ----------
__global__ __launch_bounds__(256) void hist_kernel(const float* __restrict__ obj_all,
                                                   unsigned* __restrict__ ghist,
                                                   int* __restrict__ donecnt,
                                                   unsigned* __restrict__ b1out) {
    __shared__ unsigned lh[HBINS];
    __shared__ int s_last;
    const int tid = threadIdx.x;
    const int img = blockIdx.x / NBLK, b = blockIdx.x - img * NBLK;
    int lvl, start, cnt;
    blk_span(b, lvl, start, cnt);
    const int p = img * NLVL + lvl;
    for (int i = tid; i < HBINS; i += 256) lh[i] = 0;
    __syncthreads();
    const float* o = obj_all + (size_t)img * TOTALN + start;
    for (int i = tid * 4; i < cnt; i += 1024) {        // float4: 16B/lane coalesced
        float4 v = *(const float4*)(o + i);
        atomicAdd(&lh[monokey(v.x) >> 21], 1u);
        atomicAdd(&lh[monokey(v.y) >> 21], 1u);
        atomicAdd(&lh[monokey(v.z) >> 21], 1u);
        atomicAdd(&lh[monokey(v.w) >> 21], 1u);
    }
    __syncthreads();
    unsigned* gh = ghist + (size_t)p * HBINS;
    for (int i = tid; i < HBINS; i += 256) {
        unsigned v = lh[i];
        if (v) atomicAdd(&gh[i], v);
    }
    __syncthreads();   // barrier drains vmcnt -> this block's ghist atomics are complete
    if (tid == 0) s_last = (atomicAdd(&donecnt[p], 1) == c_nch[lvl] - 1) ? 1 : 0;
    __syncthreads();
    if (!s_last) return;

    // last block for problem p: coherent re-read + suffix-sum threshold pick
    for (int i = tid; i < HBINS; i += 256) lh[i] = atomicAdd(&gh[i], 0u);
    __syncthreads();
    const int k = c_k[lvl];
    for (int d = 1; d < HBINS; d <<= 1) {
        unsigned v[HBINS / 256];
#pragma unroll
        for (int r = 0; r < HBINS / 256; ++r) {
            int i = tid + r * 256;
            v[r] = lh[i] + ((i + d < HBINS) ? lh[i + d] : 0u);
        }
        __syncthreads();
#pragma unroll
        for (int r = 0; r < HBINS / 256; ++r) lh[tid + r * 256] = v[r];
        __syncthreads();
    }
#pragma unroll
    for (int r = 0; r < HBINS / 256; ++r) {
        int i = tid + r * 256;
        if (lh[i] >= (unsigned)k && (i == HBINS - 1 || lh[i + 1] < (unsigned)k))
            b1out[p] = (unsigned)i;
    }
}

// ---------------- pass 2: compact all keys >= (b1<<21), 4096-elem float4 blocks -------
__global__ __launch_bounds__(256) void compact_kernel(const float* __restrict__ obj_all,
                                                      const unsigned* __restrict__ b1in,
                                                      int* __restrict__ cnt,
                                                      unsigned long long* __restrict__ cand) {
    __shared__ unsigned long long lkey[4096];
    __shared__ int s_lc, s_base;
    const int tid = threadIdx.x;
    const int img = blockIdx.x / NBLK, b = blockIdx.x - img * NBLK;
    int lvl, start, nrem;
    blk_span(b, lvl, start, nrem);
    const int p = img * NLVL + lvl;
    const unsigned thr = b1in[p] << 21;
    const int local0 = start - c_loff[lvl];
    if (tid == 0) s_lc = 0;
    __syncthreads();
    const float* o = obj_all + (size_t)img * TOTALN + start;
    for (int i = tid * 4; i < nrem; i += 1024) {
        float4 v = *(const float4*)(o + i);
        unsigned kx = monokey(v.x), ky = monokey(v.y);
        unsigned kz = monokey(v.z), kw = monokey(v.w);
        if (kx >= thr) { int l = atomicAdd(&s_lc, 1);
            lkey[l] = (((unsigned long long)kx) << 32) | (unsigned)(~(unsigned)(local0 + i)); }
        if (ky >= thr) { int l = atomicAdd(&s_lc, 1);
            lkey[l] = (((unsigned long long)ky) << 32) | (unsigned)(~(unsigned)(local0 + i + 1)); }
        if (kz >= thr) { int l = atomicAdd(&s_lc, 1);
            lkey[l] = (((unsigned long long)kz) << 32) | (unsigned)(~(unsigned)(local0 + i + 2)); }
        if (kw >= thr) { int l = atomicAdd(&s_lc, 1);
            lkey[l] = (((unsigned long long)kw) << 32) | (unsigned)(~(unsigned)(local0 + i + 3)); }
    }
    __syncthreads();
    if (tid == 0) s_base = atomicAdd(&cnt[p], s_lc);
    __syncthreads();
    const int lc = s_lc, base = s_base;
    unsigned long long* cd = cand + (size_t)p * CCAP;
    for (int i = tid; i < lc; i += 256) {
        int pos = base + i;
        if (pos < CCAP) cd[pos] = lkey[i];
    }
}

// ---------------- rank + decode fused: 32-deep LDS batches (MLP), 4 accumulators ------
__global__ __launch_bounds__(256) void rankdec_kernel(
    const unsigned long long* __restrict__ cand, const int* __restrict__ cnt,
    const float* __restrict__ obj_all, const float* __restrict__ deltas,
    const float* __restrict__ anchors,
    float4* __restrict__ cbox, float* __restrict__ csc, float* __restrict__ carea) {
    __shared__ unsigned long long skey[CCAP];
    const int p = blockIdx.x >> 4;
    const int blk = blockIdx.x & 15;
    const int tid = threadIdx.x;
    const int lvl = p % NLVL, img = p / NLVL, k = c_k[lvl];
    int n = cnt[p]; if (n > CCAP) n = CCAP;
    const int i0 = blk << 8;
    if (i0 >= n) return;                       // block-uniform exit, no barrier crossed
    const unsigned long long* cd = cand + (size_t)p * CCAP;
    const int n32 = (n + 31) & ~31;
    for (int i = tid; i < n32; i += 256) skey[i] = (i < n) ? cd[i] : 0ull;
    __syncthreads();
    const int i = i0 + tid;
    const unsigned long long my = (i < n) ? skey[i] : ~0ull;  // sentinel -> rank 0, not emitted
    int r0 = 0, r1 = 0, r2 = 0, r3 = 0;
    for (int j = 0; j < n32; j += 32) {        // 32 wave-uniform LDS reads in flight
        unsigned long long kk[32];
#pragma unroll
        for (int q = 0; q < 32; ++q) kk[q] = skey[j + q];
#pragma unroll
        for (int q = 0; q < 8; ++q) {
            r0 += (int)(kk[q] > my);
            r1 += (int)(kk[8 + q] > my);
            r2 += (int)(kk[16 + q] > my);
            r3 += (int)(kk[24 + q] > my);
        }
    }
    const int rank = (r0 + r1) + (r2 + r3);
    if (i < n && rank < k) {
        unsigned li = ~(unsigned)(my & 0xFFFFFFFFull);
        unsigned idx = (unsigned)c_loff[lvl] + li;
        float o = obj_all[(size_t)img * TOTALN + idx];
        const float4 dd = *(const float4*)(deltas + ((size_t)img * TOTALN + (size_t)idx) * 4);
        const float4 aa = *(const float4*)(anchors + (size_t)idx * 4);
        float a0 = aa.x, a1 = aa.y, a2 = aa.z, a3 = aa.w;
        float w = a2 - a0, h = a3 - a1;
        float cx = a0 + 0.5f * w, cy = a1 + 0.5f * h;
        float dx = dd.x, dy = dd.y;
        float dw = fminf(dd.z, BBOX_CLIP), dh = fminf(dd.w, BBOX_CLIP);
        float pcx = dx * w + cx, pcy = dy * h + cy;
        float pw = expf(dw) * w, ph = expf(dh) * h;
        float bx1 = pcx - 0.5f * pw, by1 = pcy - 0.5f * ph;
        float bx2 = pcx + 0.5f * pw, by2 = pcy + 0.5f * ph;
        float x1 = fminf(fmaxf(bx1, 0.f), IMGSZ);
        float y1 = fminf(fmaxf(by1, 0.f), IMGSZ);
        float x2 = fminf(fmaxf(bx2, 0.f), IMGSZ);
        float y2 = fminf(fmaxf(by2, 0.f), IMGSZ);
        float wsz = x2 - x1, hsz = y2 - y1;
        float scv = (wsz >= MINSZ && hsz >= MINSZ) ? 1.0f / (1.0f + expf(-o)) : 0.0f;
        cbox[(size_t)p * CAP + rank] = make_float4(x1, y1, x2, y2);
        csc[(size_t)p * CAP + rank] = scv;
        carea[(size_t)p * CAP + rank] = wsz * hsz;   // same expression the mask used
    }
}

// ---------------- NMS phase 1: suppressed-by mask S[rc][col] ----------------
__global__ __launch_bounds__(256) void mask_kernel(const float4* __restrict__ cbox,
                                                   const float* __restrict__ carea,
                                                   unsigned long long* __restrict__ gmaskS) {
    const int bid = blockIdx.x;
    const int p = bid / 34;
    const int wid = __builtin_amdgcn_readfirstlane(threadIdx.x >> 6);
    const int lane = threadIdx.x & 63;
    const int q = (bid - p * 34) * 4 + wid;           // 0..135, SGPR
    const int w = c_pw[q], rc = c_pr[q];              // SGPR via scalar loads
    const int base = p * CAP;

    const float4 cb = cbox[base + (w << 6) + lane];   // column box, per-lane registers
    const float car = carea[base + (w << 6) + lane];
    const float4* rowb = cbox + base + (rc << 6);     // wave-uniform row pointers
    const float* rowa = carea + base + (rc << 6);

    unsigned slo = 0, shi = 0;
#pragma unroll 8
    for (int r = 0; r < 64; ++r) {
        const float4 rb = rowb[r];                    // s_load_dwordx4 (uniform)
        const float ar = rowa[r];                     // s_load_dword  (uniform)
        float ltx = fmaxf(rb.x, cb.x), lty = fmaxf(rb.y, cb.y);
        float rbx = fminf(rb.z, cb.z), rby = fminf(rb.w, cb.w);
        float wx = fmaxf(rbx - ltx, 0.f), wy = fmaxf(rby - lty, 0.f);
        float inter = wx * wy;
        float un = (ar + car) - inter;
        bool sup = (un > 0.f) && ((double)inter >= M_TH * (double)un);
        if (r < 32) slo |= sup ? (1u << r) : 0u;
        else        shi |= sup ? (1u << (r - 32)) : 0u;
    }
    unsigned long long sbits = (((unsigned long long)shi) << 32) | slo;
    if (rc == w) sbits &= ((1ull << lane) - 1ull);    // diag: strictly lower rows only
    gmaskS[(((size_t)(p * 16 + rc)) << 10) + (w << 6) + lane] = sbits;
}

// ---------------- NMS phase 2: register greedy scan, no LDS mask copy -----------------
__global__ __launch_bounds__(256) void scan_kernel(
    const unsigned long long* __restrict__ gmaskS,
    const float4* __restrict__ cbox, const float* __restrict__ csc,
    float* __restrict__ svbox, float* __restrict__ svsc, int* __restrict__ svcnt) {
    __shared__ float ssc[CAP];
    __shared__ unsigned short survL[CAP];
    __shared__ int s_ns;
    const int p = blockIdx.x, tid = threadIdx.x;
    const int lvl = p % NLVL, k = c_k[lvl];
    const int base = p * CAP;
    for (int i = tid; i < CAP; i += 256) ssc[i] = (i < k) ? csc[base + i] : 0.f;
    __syncthreads();

    if (tid < 64) {
        const int lane = tid;
        const unsigned long long mybit = 1ull << lane;
        const unsigned long long below = mybit - 1ull;
        const unsigned long long* gS = gmaskS + ((size_t)p << 14);   // p*16*1024
        unsigned long long aw[16];
        int ns = 0;
#pragma unroll
        for (int g = 0; g < 16; ++g) {
            unsigned long long kk[16];
#pragma unroll
            for (int rc = 0; rc <= g; ++rc)                  // coalesced 512B each
                kk[rc] = gS[(((size_t)rc) << 10) + (g << 6) + lane];
            unsigned long long wv = __ballot(ssc[(g << 6) + lane] <= 0.f);
            unsigned long long killed = 0;
#pragma unroll
            for (int w2 = 0; w2 < g; ++w2) killed |= kk[w2] & aw[w2];
            const unsigned long long kmask = __ballot(killed != 0ull);
            const unsigned long long alive = ~(wv | kmask);
            const unsigned long long dg = kk[g];             // strict-lower diag word
            unsigned long long A = alive;
#pragma unroll 1
            for (int it = 0; it < 64; ++it) {                // fixpoint -> exact greedy
                bool kill = (dg & A) != 0ull;
                unsigned long long An = alive & ~__ballot(kill);
                if (An == A) break;
                A = An;
            }
            if (A & mybit)                                   // parallel, ordered emission
                survL[ns + __popcll(A & below)] = (unsigned short)((g << 6) + lane);
            ns += __popcll(A);
            aw[g] = A;
        }
        if (lane == 0) s_ns = ns;
    }
    __syncthreads();

    const int ns = s_ns;
    for (int s = tid; s < ns; s += 256) {
        int r = survL[s];
        svsc[base + s] = ssc[r];
        *(float4*)(svbox + ((size_t)(base + s)) * 4) = cbox[base + r];
    }
    if (tid == 0) svcnt[p] = ns;
}

// ---------------- merge: 80 blocks (img,level); branchless bit-descent rank ----------
__global__ __launch_bounds__(256) void merge_kernel(
    const float* __restrict__ svbox, const float* __restrict__ svsc,
    const int* __restrict__ svcnt, float* __restrict__ out) {
    __shared__ float sls[NLVL][CAP];
    __shared__ int scnt[NLVL];
    const int img = blockIdx.x / NLVL, l = blockIdx.x % NLVL;
    const int tid = threadIdx.x;
    if (tid < NLVL) scnt[tid] = svcnt[img * NLVL + tid];
    __syncthreads();
    for (int m = 0; m < NLVL; ++m) {
        int c = scnt[m];
        for (int i = tid; i < c; i += 256) sls[m][i] = svsc[(img * NLVL + m) * CAP + i];
    }
    __syncthreads();
    const int c = scnt[l];
    for (int i = tid; i < c; i += 256) {
        const float s = sls[l][i];
        int pos = i;
#pragma unroll
        for (int m = 0; m < NLVL; ++m) {
            if (m == l) continue;
            const int n2 = scnt[m];
            int lo = 0;
#pragma unroll
            for (int st = 512; st > 0; st >>= 1) {
                const int idx = lo + st;
                const bool ok = (idx <= n2);
                const float v = sls[m][ok ? idx - 1 : 0];   // in-bounds; unused if !ok
                const bool ahead = (m < l) ? (v >= s) : (v > s);
                if (ok && ahead) lo = idx;
            }
            pos += lo;
        }
        if (pos < POST_N) {
            const int src = (img * NLVL + l) * CAP + i;
            float* o = out + ((size_t)img * POST_N + pos) * 5;
            o[0] = svbox[(size_t)src * 4 + 0];
            o[1] = svbox[(size_t)src * 4 + 1];
            o[2] = svbox[(size_t)src * 4 + 2];
            o[3] = svbox[(size_t)src * 4 + 3];
            o[4] = s;
        }
    }
}

extern "C" void kernel_launch(void* const* d_in, const int* in_sizes, int n_in,
                              void* d_out, int out_size, void* d_ws, size_t ws_size,
                              hipStream_t stream) {
    const float* obj     = (const float*)d_in[0];
    const float* deltas  = (const float*)d_in[1];
    const float* anchors = (const float*)d_in[2];
    float* out = (float*)d_out;

    char* w = (char*)d_ws;
    size_t off = 0;
    auto alloc = [&](size_t bytes) -> void* {
        void* pp = w + off;
        off += (bytes + 511) & ~(size_t)511;
        return pp;
    };
    // zeroed region: ghist + donecnt + ccnt cleared by zero_kernel (one launch)
    size_t z0 = off;
    unsigned* ghist   = (unsigned*)alloc((size_t)NPROB * HBINS * 4);
    int*      donecnt = (int*)alloc((size_t)NPROB * 4);
    int*      ccnt    = (int*)alloc((size_t)NPROB * 4);
    size_t zspan = off - z0;
    unsigned* b1buf = (unsigned*)alloc((size_t)NPROB * 4);
    unsigned long long* cand = (unsigned long long*)alloc((size_t)NPROB * CCAP * 8);
    float4*   cbox  = (float4*)alloc((size_t)NPROB * CAP * 16);
    float*    csc   = (float*)alloc((size_t)NPROB * CAP * 4);
    float*    carea = (float*)alloc((size_t)NPROB * CAP * 4);
    unsigned long long* gmaskS = (unsigned long long*)alloc((size_t)NPROB * 16 * CAP * 8);
    float* svbox = (float*)alloc((size_t)NPROB * CAP * 16);
    float* svsc  = (float*)alloc((size_t)NPROB * CAP * 4);
    int*   svcnt = (int*)alloc((size_t)NPROB * 4);
    if (off > ws_size) return;  // fail cleanly (output stays poisoned -> visible failure)

    const int na = (int)(zspan / 16);                       // zspan is 512B-multiple
    const int nb = (int)((size_t)out_size * sizeof(float) / 16);  // 320000B = 20000*16
    const int nz = (na > nb ? na : nb);
    zero_kernel<<<(nz + 255) / 256, 256, 0, stream>>>((ulonglong2*)(w + z0), na,
                                                      (ulonglong2*)out, nb);

    hist_kernel<<<NBATCH * NBLK, 256, 0, stream>>>(obj, ghist, donecnt, b1buf);
    compact_kernel<<<NBATCH * NBLK, 256, 0, stream>>>(obj, b1buf, ccnt, cand);
    rankdec_kernel<<<NPROB * 16, 256, 0, stream>>>(cand, ccnt, obj, deltas, anchors,
                                                   cbox, csc, carea);
    mask_kernel<<<NPROB * 34, 256, 0, stream>>>(cbox, carea, gmaskS);
    scan_kernel<<<NPROB, 256, 0, stream>>>(gmaskS, cbox, csc, svbox, svsc, svcnt);
    merge_kernel<<<NPROB, 256, 0, stream>>>(svbox, svsc, svcnt, out);
}

// Round 22
// 134.220 us; speedup vs baseline: 1.3844x; 1.0120x over previous
//
#include <hip/hip_runtime.h>
#include <math.h>

#pragma clang fp contract(off)

#define NLVL 5
#define TOTALN 261888
#define NBATCH 16
#define CAP 1024
#define NPROB (NBATCH * NLVL)
#define POST_N 1000
#define NMS_TH 0.7f
#define MINSZ 1e-3f
#define IMGSZ 1024.0f
#define BBOX_CLIP 4.135166556742356f

// exact midpoint between 0.7f and nextafterf(0.7f): fl32(a/b) > 0.7f  <=>  a >= M_TH*b (b>0)
// (0.7f mantissa odd -> round-to-nearest-even sends the tie upward -> ">="); 25-bit M_TH
// times 24-bit un is exact in double, and (double)inter is exact -> predicate is exact.
#define M_TH 0x1.666667p-1

#define HBINS 2048
#define CCAP 4096
#define NBLK 65      // compact blocks per image (48+12+3+1+1), 4096-elem spans
#define NBLKH 18     // hist blocks per image (12+3+1+1+1), 16384-elem spans
#define NPAIR 136    // (w, rc<=w) wave-pairs per problem; 34 blocks x 4 waves

__constant__ int c_loff[NLVL] = {0, 196608, 245760, 258048, 261120};
__constant__ int c_k[NLVL]    = {1000, 1000, 1000, 1000, 768};
__constant__ int c_nch[NLVL]  = {12, 3, 1, 1, 1};      // hist blocks per level

// pair q -> (word w, row-chunk rc), rc <= w, q = w(w+1)/2 + rc
__constant__ unsigned char c_pw[NPAIR] = {
    0, 1,1, 2,2,2, 3,3,3,3, 4,4,4,4,4, 5,5,5,5,5,5, 6,6,6,6,6,6,6,
    7,7,7,7,7,7,7,7, 8,8,8,8,8,8,8,8,8, 9,9,9,9,9,9,9,9,9,9,
    10,10,10,10,10,10,10,10,10,10,10, 11,11,11,11,11,11,11,11,11,11,11,11,
    12,12,12,12,12,12,12,12,12,12,12,12,12, 13,13,13,13,13,13,13,13,13,13,13,13,13,13,
    14,14,14,14,14,14,14,14,14,14,14,14,14,14,14,
    15,15,15,15,15,15,15,15,15,15,15,15,15,15,15,15};
__constant__ unsigned char c_pr[NPAIR] = {
    0, 0,1, 0,1,2, 0,1,2,3, 0,1,2,3,4, 0,1,2,3,4,5, 0,1,2,3,4,5,6,
    0,1,2,3,4,5,6,7, 0,1,2,3,4,5,6,7,8, 0,1,2,3,4,5,6,7,8,9,
    0,1,2,3,4,5,6,7,8,9,10, 0,1,2,3,4,5,6,7,8,9,10,11,
    0,1,2,3,4,5,6,7,8,9,10,11,12, 0,1,2,3,4,5,6,7,8,9,10,11,12,13,
    0,1,2,3,4,5,6,7,8,9,10,11,12,13,14,
    0,1,2,3,4,5,6,7,8,9,10,11,12,13,14,15};

__device__ __forceinline__ unsigned monokey(float f) {
    unsigned b = __float_as_uint(f);
    return (b & 0x80000000u) ? ~b : (b | 0x80000000u);
}

// compact block b in [0,NBLK): 4096-elem spans; spans never straddle levels
__device__ __forceinline__ void blk_span(int b, int& lvl, int& start, int& cnt) {
    if (b < 48)      { lvl = 0; start = b * 4096;                  cnt = 4096; }
    else if (b < 60) { lvl = 1; start = 196608 + (b - 48) * 4096;  cnt = 4096; }
    else if (b < 63) { lvl = 2; start = 245760 + (b - 60) * 4096;  cnt = 4096; }
    else if (b == 63){ lvl = 3; start = 258048;                    cnt = 3072; }
    else             { lvl = 4; start = 261120;                    cnt = 768;  }
}

// hist block b in [0,NBLKH): 16384-elem spans (hist streams, needs no element staging)
__device__ __forceinline__ void blk_span_h(int b, int& lvl, int& start, int& cnt) {
    if (b < 12)      { lvl = 0; start = b * 16384;                 cnt = 16384; }
    else if (b < 15) { lvl = 1; start = 196608 + (b - 12) * 16384; cnt = 16384; }
    else if (b == 15){ lvl = 2; start = 245760;                    cnt = 12288; }
    else if (b == 16){ lvl = 3; start = 258048;                    cnt = 3072;  }
    else             { lvl = 4; start = 261120;                    cnt = 768;   }
}

// ---------------- custom zero (runtime's small fillBuffer kernel is latency-bound) ----
__global__ __launch_bounds__(256) void zero_kernel(ulonglong2* __restrict__ a, int na,
                                                   ulonglong2* __restrict__ b, int nb) {
    const int i = blockIdx.x * 256 + threadIdx.x;
    const ulonglong2 z = make_ulonglong2(0ull, 0ull);
    if (i < na) a[i] = z;
    if (i < nb) b[i] = z;
}

// ---------------- pass 1: 16384-elem float4 histogram + fused last-block pick ---------
__global__ __launch_bounds__(256) void hist_kernel(const float* __restrict__ obj_all,
                                                   unsigned* __restrict__ ghist,
                                                   int* __restrict__ donecnt,
                                                   unsigned* __restrict__ b1out) {
    __shared__ unsigned lh[HBINS];
    __shared__ int s_last;
    const int tid = threadIdx.x;
    const int img = blockIdx.x / NBLKH, b = blockIdx.x - img * NBLKH;
    int lvl, start, cnt;
    blk_span_h(b, lvl, start, cnt);
    const int p = img * NLVL + lvl;
    for (int i = tid; i < HBINS; i += 256) lh[i] = 0;
    __syncthreads();
    const float* o = obj_all + (size_t)img * TOTALN + start;
    for (int i = tid * 4; i < cnt; i += 1024) {        // float4: 16B/lane coalesced
        float4 v = *(const float4*)(o + i);
        atomicAdd(&lh[monokey(v.x) >> 21], 1u);
        atomicAdd(&lh[monokey(v.y) >> 21], 1u);
        atomicAdd(&lh[monokey(v.z) >> 21], 1u);
        atomicAdd(&lh[monokey(v.w) >> 21], 1u);
    }
    __syncthreads();
    unsigned* gh = ghist + (size_t)p * HBINS;
    for (int i = tid; i < HBINS; i += 256) {
        unsigned v = lh[i];
        if (v) atomicAdd(&gh[i], v);
    }
    __syncthreads();   // barrier drains vmcnt -> this block's ghist atomics are complete
    if (tid == 0) s_last = (atomicAdd(&donecnt[p], 1) == c_nch[lvl] - 1) ? 1 : 0;
    __syncthreads();
    if (!s_last) return;

    // last block for problem p: coherent re-read + suffix-sum threshold pick
    for (int i = tid; i < HBINS; i += 256) lh[i] = atomicAdd(&gh[i], 0u);
    __syncthreads();
    const int k = c_k[lvl];
    for (int d = 1; d < HBINS; d <<= 1) {
        unsigned v[HBINS / 256];
#pragma unroll
        for (int r = 0; r < HBINS / 256; ++r) {
            int i = tid + r * 256;
            v[r] = lh[i] + ((i + d < HBINS) ? lh[i + d] : 0u);
        }
        __syncthreads();
#pragma unroll
        for (int r = 0; r < HBINS / 256; ++r) lh[tid + r * 256] = v[r];
        __syncthreads();
    }
#pragma unroll
    for (int r = 0; r < HBINS / 256; ++r) {
        int i = tid + r * 256;
        if (lh[i] >= (unsigned)k && (i == HBINS - 1 || lh[i + 1] < (unsigned)k))
            b1out[p] = (unsigned)i;
    }
}

// ---------------- pass 2: compact all keys >= (b1<<21), 4096-elem float4 blocks -------
__global__ __launch_bounds__(256) void compact_kernel(const float* __restrict__ obj_all,
                                                      const unsigned* __restrict__ b1in,
                                                      int* __restrict__ cnt,
                                                      unsigned long long* __restrict__ cand) {
    __shared__ unsigned long long lkey[4096];
    __shared__ int s_lc, s_base;
    const int tid = threadIdx.x;
    const int img = blockIdx.x / NBLK, b = blockIdx.x - img * NBLK;
    int lvl, start, nrem;
    blk_span(b, lvl, start, nrem);
    const int p = img * NLVL + lvl;
    const unsigned thr = b1in[p] << 21;
    const int local0 = start - c_loff[lvl];
    if (tid == 0) s_lc = 0;
    __syncthreads();
    const float* o = obj_all + (size_t)img * TOTALN + start;
    for (int i = tid * 4; i < nrem; i += 1024) {
        float4 v = *(const float4*)(o + i);
        unsigned kx = monokey(v.x), ky = monokey(v.y);
        unsigned kz = monokey(v.z), kw = monokey(v.w);
        if (kx >= thr) { int l = atomicAdd(&s_lc, 1);
            lkey[l] = (((unsigned long long)kx) << 32) | (unsigned)(~(unsigned)(local0 + i)); }
        if (ky >= thr) { int l = atomicAdd(&s_lc, 1);
            lkey[l] = (((unsigned long long)ky) << 32) | (unsigned)(~(unsigned)(local0 + i + 1)); }
        if (kz >= thr) { int l = atomicAdd(&s_lc, 1);
            lkey[l] = (((unsigned long long)kz) << 32) | (unsigned)(~(unsigned)(local0 + i + 2)); }
        if (kw >= thr) { int l = atomicAdd(&s_lc, 1);
            lkey[l] = (((unsigned long long)kw) << 32) | (unsigned)(~(unsigned)(local0 + i + 3)); }
    }
    __syncthreads();
    if (tid == 0) s_base = atomicAdd(&cnt[p], s_lc);
    __syncthreads();
    const int lc = s_lc, base = s_base;
    unsigned long long* cd = cand + (size_t)p * CCAP;
    for (int i = tid; i < lc; i += 256) {
        int pos = base + i;
        if (pos < CCAP) cd[pos] = lkey[i];
    }
}

// ---------------- rank + decode fused: 32-deep LDS batches (MLP), 4 accumulators ------
__global__ __launch_bounds__(256) void rankdec_kernel(
    const unsigned long long* __restrict__ cand, const int* __restrict__ cnt,
    const float* __restrict__ obj_all, const float* __restrict__ deltas,
    const float* __restrict__ anchors,
    float4* __restrict__ cbox, float* __restrict__ csc, float* __restrict__ carea) {
    __shared__ unsigned long long skey[CCAP];
    const int p = blockIdx.x >> 4;
    const int blk = blockIdx.x & 15;
    const int tid = threadIdx.x;
    const int lvl = p % NLVL, img = p / NLVL, k = c_k[lvl];
    int n = cnt[p]; if (n > CCAP) n = CCAP;
    const int i0 = blk << 8;
    if (i0 >= n) return;                       // block-uniform exit, no barrier crossed
    const unsigned long long* cd = cand + (size_t)p * CCAP;
    const int n32 = (n + 31) & ~31;
    for (int i = tid; i < n32; i += 256) skey[i] = (i < n) ? cd[i] : 0ull;
    __syncthreads();
    const int i = i0 + tid;
    const unsigned long long my = (i < n) ? skey[i] : ~0ull;  // sentinel -> rank 0, not emitted
    int r0 = 0, r1 = 0, r2 = 0, r3 = 0;
    for (int j = 0; j < n32; j += 32) {        // 32 wave-uniform LDS reads in flight
        unsigned long long kk[32];
#pragma unroll
        for (int q = 0; q < 32; ++q) kk[q] = skey[j + q];
#pragma unroll
        for (int q = 0; q < 8; ++q) {
            r0 += (int)(kk[q] > my);
            r1 += (int)(kk[8 + q] > my);
            r2 += (int)(kk[16 + q] > my);
            r3 += (int)(kk[24 + q] > my);
        }
    }
    const int rank = (r0 + r1) + (r2 + r3);
    if (i < n && rank < k) {
        unsigned li = ~(unsigned)(my & 0xFFFFFFFFull);
        unsigned idx = (unsigned)c_loff[lvl] + li;
        float o = obj_all[(size_t)img * TOTALN + idx];
        const float4 dd = *(const float4*)(deltas + ((size_t)img * TOTALN + (size_t)idx) * 4);
        const float4 aa = *(const float4*)(anchors + (size_t)idx * 4);
        float a0 = aa.x, a1 = aa.y, a2 = aa.z, a3 = aa.w;
        float w = a2 - a0, h = a3 - a1;
        float cx = a0 + 0.5f * w, cy = a1 + 0.5f * h;
        float dx = dd.x, dy = dd.y;
        float dw = fminf(dd.z, BBOX_CLIP), dh = fminf(dd.w, BBOX_CLIP);
        float pcx = dx * w + cx, pcy = dy * h + cy;
        float pw = expf(dw) * w, ph = expf(dh) * h;
        float bx1 = pcx - 0.5f * pw, by1 = pcy - 0.5f * ph;
        float bx2 = pcx + 0.5f * pw, by2 = pcy + 0.5f * ph;
        float x1 = fminf(fmaxf(bx1, 0.f), IMGSZ);
        float y1 = fminf(fmaxf(by1, 0.f), IMGSZ);
        float x2 = fminf(fmaxf(bx2, 0.f), IMGSZ);
        float y2 = fminf(fmaxf(by2, 0.f), IMGSZ);
        float wsz = x2 - x1, hsz = y2 - y1;
        float scv = (wsz >= MINSZ && hsz >= MINSZ) ? 1.0f / (1.0f + expf(-o)) : 0.0f;
        cbox[(size_t)p * CAP + rank] = make_float4(x1, y1, x2, y2);
        csc[(size_t)p * CAP + rank] = scv;
        carea[(size_t)p * CAP + rank] = wsz * hsz;   // same expression the mask used
    }
}

// ---------------- NMS phase 1: suppressed-by mask S[rc][col], batched s_loads ---------
// Wave (w, rc): lane = col 64w+lane. sbits bit r = (row rc*64+r suppresses col).
// Two-phase 8-row batches: 16 independent scalar loads issued together, then 8 bodies.
__global__ __launch_bounds__(256) void mask_kernel(const float4* __restrict__ cbox,
                                                   const float* __restrict__ carea,
                                                   unsigned long long* __restrict__ gmaskS) {
    const int bid = blockIdx.x;
    const int p = bid / 34;
    const int wid = __builtin_amdgcn_readfirstlane(threadIdx.x >> 6);
    const int lane = threadIdx.x & 63;
    const int q = (bid - p * 34) * 4 + wid;           // 0..135, SGPR
    const int w = c_pw[q], rc = c_pr[q];              // SGPR via scalar loads
    const int base = p * CAP;

    const float4 cb = cbox[base + (w << 6) + lane];   // column box, per-lane registers
    const float car = carea[base + (w << 6) + lane];
    const float4* rowb = cbox + base + (rc << 6);     // wave-uniform row pointers
    const float* rowa = carea + base + (rc << 6);

    unsigned slo = 0, shi = 0;
    for (int rb0 = 0; rb0 < 64; rb0 += 8) {
        float4 rb[8]; float ar[8];
#pragma unroll
        for (int t = 0; t < 8; ++t) {                 // batched uniform s_loads (MLP)
            rb[t] = rowb[rb0 + t];
            ar[t] = rowa[rb0 + t];
        }
#pragma unroll
        for (int t = 0; t < 8; ++t) {
            const int r = rb0 + t;
            float ltx = fmaxf(rb[t].x, cb.x), lty = fmaxf(rb[t].y, cb.y);
            float rbx = fminf(rb[t].z, cb.z), rby = fminf(rb[t].w, cb.w);
            float wx = fmaxf(rbx - ltx, 0.f), wy = fmaxf(rby - lty, 0.f);
            float inter = wx * wy;
            float un = (ar[t] + car) - inter;
            bool sup = (un > 0.f) && ((double)inter >= M_TH * (double)un);
            if (r < 32) slo |= sup ? (1u << r) : 0u;
            else        shi |= sup ? (1u << (r - 32)) : 0u;
        }
    }
    unsigned long long sbits = (((unsigned long long)shi) << 32) | slo;
    if (rc == w) sbits &= ((1ull << lane) - 1ull);    // diag: strictly lower rows only
    gmaskS[(((size_t)(p * 16 + rc)) << 10) + (w << 6) + lane] = sbits;
}

// ---------------- NMS phase 2: register greedy scan, no LDS mask copy -----------------
__global__ __launch_bounds__(256) void scan_kernel(
    const unsigned long long* __restrict__ gmaskS,
    const float4* __restrict__ cbox, const float* __restrict__ csc,
    float* __restrict__ svbox, float* __restrict__ svsc, int* __restrict__ svcnt) {
    __shared__ float ssc[CAP];
    __shared__ unsigned short survL[CAP];
    __shared__ int s_ns;
    const int p = blockIdx.x, tid = threadIdx.x;
    const int lvl = p % NLVL, k = c_k[lvl];
    const int base = p * CAP;
    for (int i = tid; i < CAP; i += 256) ssc[i] = (i < k) ? csc[base + i] : 0.f;
    __syncthreads();

    if (tid < 64) {
        const int lane = tid;
        const unsigned long long mybit = 1ull << lane;
        const unsigned long long below = mybit - 1ull;
        const unsigned long long* gS = gmaskS + ((size_t)p << 14);   // p*16*1024
        unsigned long long aw[16];
        int ns = 0;
#pragma unroll
        for (int g = 0; g < 16; ++g) {
            unsigned long long kk[16];
#pragma unroll
            for (int rc = 0; rc <= g; ++rc)                  // coalesced 512B each
                kk[rc] = gS[(((size_t)rc) << 10) + (g << 6) + lane];
            unsigned long long wv = __ballot(ssc[(g << 6) + lane] <= 0.f);
            unsigned long long killed = 0;
#pragma unroll
            for (int w2 = 0; w2 < g; ++w2) killed |= kk[w2] & aw[w2];
            const unsigned long long kmask = __ballot(killed != 0ull);
            const unsigned long long alive = ~(wv | kmask);
            const unsigned long long dg = kk[g];             // strict-lower diag word
            unsigned long long A = alive;
#pragma unroll 1
            for (int it = 0; it < 64; ++it) {                // fixpoint -> exact greedy
                bool kill = (dg & A) != 0ull;
                unsigned long long An = alive & ~__ballot(kill);
                if (An == A) break;
                A = An;
            }
            if (A & mybit)                                   // parallel, ordered emission
                survL[ns + __popcll(A & below)] = (unsigned short)((g << 6) + lane);
            ns += __popcll(A);
            aw[g] = A;
        }
        if (lane == 0) s_ns = ns;
    }
    __syncthreads();

    const int ns = s_ns;
    for (int s = tid; s < ns; s += 256) {
        int r = survL[s];
        svsc[base + s] = ssc[r];
        *(float4*)(svbox + ((size_t)(base + s)) * 4) = cbox[base + r];
    }
    if (tid == 0) svcnt[p] = ns;
}

// ---------------- merge: 80 blocks (img,level); branchless bit-descent rank ----------
__global__ __launch_bounds__(256) void merge_kernel(
    const float* __restrict__ svbox, const float* __restrict__ svsc,
    const int* __restrict__ svcnt, float* __restrict__ out) {
    __shared__ float sls[NLVL][CAP];
    __shared__ int scnt[NLVL];
    const int img = blockIdx.x / NLVL, l = blockIdx.x % NLVL;
    const int tid = threadIdx.x;
    if (tid < NLVL) scnt[tid] = svcnt[img * NLVL + tid];
    __syncthreads();
    for (int m = 0; m < NLVL; ++m) {
        int c = scnt[m];
        for (int i = tid; i < c; i += 256) sls[m][i] = svsc[(img * NLVL + m) * CAP + i];
    }
    __syncthreads();
    const int c = scnt[l];
    for (int i = tid; i < c; i += 256) {
        const float s = sls[l][i];
        int pos = i;
#pragma unroll
        for (int m = 0; m < NLVL; ++m) {
            if (m == l) continue;
            const int n2 = scnt[m];
            int lo = 0;
#pragma unroll
            for (int st = 512; st > 0; st >>= 1) {
                const int idx = lo + st;
                const bool ok = (idx <= n2);
                const float v = sls[m][ok ? idx - 1 : 0];   // in-bounds; unused if !ok
                const bool ahead = (m < l) ? (v >= s) : (v > s);
                if (ok && ahead) lo = idx;
            }
            pos += lo;
        }
        if (pos < POST_N) {
            const int src = (img * NLVL + l) * CAP + i;
            float* o = out + ((size_t)img * POST_N + pos) * 5;
            o[0] = svbox[(size_t)src * 4 + 0];
            o[1] = svbox[(size_t)src * 4 + 1];
            o[2] = svbox[(size_t)src * 4 + 2];
            o[3] = svbox[(size_t)src * 4 + 3];
            o[4] = s;
        }
    }
}

extern "C" void kernel_launch(void* const* d_in, const int* in_sizes, int n_in,
                              void* d_out, int out_size, void* d_ws, size_t ws_size,
                              hipStream_t stream) {
    const float* obj     = (const float*)d_in[0];
    const float* deltas  = (const float*)d_in[1];
    const float* anchors = (const float*)d_in[2];
    float* out = (float*)d_out;

    char* w = (char*)d_ws;
    size_t off = 0;
    auto alloc = [&](size_t bytes) -> void* {
        void* pp = w + off;
        off += (bytes + 511) & ~(size_t)511;
        return pp;
    };
    // zeroed region: ghist + donecnt + ccnt cleared by zero_kernel (one launch)
    size_t z0 = off;
    unsigned* ghist   = (unsigned*)alloc((size_t)NPROB * HBINS * 4);
    int*      donecnt = (int*)alloc((size_t)NPROB * 4);
    int*      ccnt    = (int*)alloc((size_t)NPROB * 4);
    size_t zspan = off - z0;
    unsigned* b1buf = (unsigned*)alloc((size_t)NPROB * 4);
    unsigned long long* cand = (unsigned long long*)alloc((size_t)NPROB * CCAP * 8);
    float4*   cbox  = (float4*)alloc((size_t)NPROB * CAP * 16);
    float*    csc   = (float*)alloc((size_t)NPROB * CAP * 4);
    float*    carea = (float*)alloc((size_t)NPROB * CAP * 4);
    unsigned long long* gmaskS = (unsigned long long*)alloc((size_t)NPROB * 16 * CAP * 8);
    float* svbox = (float*)alloc((size_t)NPROB * CAP * 16);
    float* svsc  = (float*)alloc((size_t)NPROB * CAP * 4);
    int*   svcnt = (int*)alloc((size_t)NPROB * 4);
    if (off > ws_size) return;  // fail cleanly (output stays poisoned -> visible failure)

    const int na = (int)(zspan / 16);                       // zspan is 512B-multiple
    const int nb = (int)((size_t)out_size * sizeof(float) / 16);  // 320000B = 20000*16
    const int nz = (na > nb ? na : nb);
    zero_kernel<<<(nz + 255) / 256, 256, 0, stream>>>((ulonglong2*)(w + z0), na,
                                                      (ulonglong2*)out, nb);

    hist_kernel<<<NBATCH * NBLKH, 256, 0, stream>>>(obj, ghist, donecnt, b1buf);
    compact_kernel<<<NBATCH * NBLK, 256, 0, stream>>>(obj, b1buf, ccnt, cand);
    rankdec_kernel<<<NPROB * 16, 256, 0, stream>>>(cand, ccnt, obj, deltas, anchors,
                                                   cbox, csc, carea);
    mask_kernel<<<NPROB * 34, 256, 0, stream>>>(cbox, carea, gmaskS);
    scan_kernel<<<NPROB, 256, 0, stream>>>(gmaskS, cbox, csc, svbox, svsc, svcnt);
    merge_kernel<<<NPROB, 256, 0, stream>>>(svbox, svsc, svcnt, out);
}